// Round 1
// baseline (2054.468 us; speedup 1.0000x reference)
//
#include <hip/hip_runtime.h>
#include <hip/hip_bf16.h>
#include <math.h>

#define BB 64
#define SS 512
#define HH 64
#define DD 128
#define NHD 8
#define ROWS (BB*SS)   // 32768

typedef unsigned short u16;
typedef __attribute__((ext_vector_type(8))) short bf16x8;
typedef __attribute__((ext_vector_type(4))) float f32x4;

__device__ __forceinline__ u16 f2b(float f) {
  union { float f; unsigned u; } x; x.f = f;
  unsigned r = x.u + 0x7fffu + ((x.u >> 16) & 1u);
  return (u16)(r >> 16);
}

__device__ __forceinline__ float b2f(u16 u) {
  return __uint_as_float(((unsigned)u) << 16);
}

__device__ __forceinline__ float fast_tanh(float x) {
  float ax = fminf(fabsf(x), 15.f);
  float e = __expf(2.f * ax);
  float r = 1.f - __fdividef(2.f, e + 1.f);
  return copysignf(r, x);
}

__device__ __forceinline__ void barrier_lds() {
  __builtin_amdgcn_s_waitcnt(0xC07F);   // lgkmcnt(0) only
  __builtin_amdgcn_s_barrier();
}

__device__ __forceinline__ void wait_lds() {
  __builtin_amdgcn_s_waitcnt(0xC07F);   // lgkmcnt(0), intra-wave LDS RAW
}

// ---------------------------------------------------------------------------
// SDE scan v7: 2 waves/block, wave 0 = drift net (A->B->C), wave 1 =
// diffusion net (A->B). All weights register-resident (~322 f32/lane,
// launch_bounds(128,1) -> large VGPR budget, overflow goes to AGPRs).
// Intra-wave stage handoffs use LDS + lgkmcnt only (no barrier); the single
// cross-wave dependency (h2/gc) uses ONE 2-wave barrier per step with
// parity double-buffering. Stage C is computed redundantly on both waves so
// each wave updates a private y-copy (no second barrier). Noise prefetched
// 4 steps deep via a shift register (compile-time indices, no scratch).
// ---------------------------------------------------------------------------
__global__ __launch_bounds__(128, 1) void sde_kernel(
    const float* __restrict__ ts, const float* __restrict__ noise,
    const float* __restrict__ dW1, const float* __restrict__ db1,
    const float* __restrict__ dW2, const float* __restrict__ db2,
    const float* __restrict__ dW3, const float* __restrict__ db3,
    const float* __restrict__ gW1, const float* __restrict__ gb1,
    const float* __restrict__ gW2, const float* __restrict__ gb2,
    const float* __restrict__ pmind, const float* __restrict__ pmaxd,
    float* __restrict__ out, u16* __restrict__ outB) {
  const int b = blockIdx.x, t = threadIdx.x;
  const int w = t >> 6, lane = t & 63;

  __shared__ float y_s[2][64];        // per-wave private y copy
  __shared__ float h1s[2][128];       // per-wave private stage-A output
  __shared__ float h2s[2][64];        // drift hidden, parity double-buffered
  __shared__ float gcs[2][64];        // diffusion out, parity double-buffered
  __shared__ float tl_s[512], hs_s[512], sq_s[512];

  const float mind = fabsf(pmind[0]);
  const float maxd = fabsf(pmaxd[0]);

  // ---- register-resident weights (per-wave network) ----
  const float* W1  = w ? gW1 : dW1;
  const float* W2  = w ? gW2 : dW2;
  const float* b1p = w ? gb1 : db1;
  const float* b2p = w ? gb2 : db2;

  float wa0[64], wa1[64], wb[128], wc[64];
#pragma unroll
  for (int k = 0; k < 64; k++) wa0[k] = W1[k * 128 + lane];
#pragma unroll
  for (int k = 0; k < 64; k++) wa1[k] = W1[k * 128 + 64 + lane];
  const float wt0 = W1[64 * 128 + lane];
  const float wt1 = W1[64 * 128 + 64 + lane];
  const float bA0 = b1p[lane], bA1 = b1p[64 + lane];
#pragma unroll
  for (int k = 0; k < 128; k++) wb[k] = W2[k * 64 + lane];
  const float bB = b2p[lane];
#pragma unroll
  for (int k = 0; k < 64; k++) wc[k] = dW3[k * 64 + lane];
  const float bC = db3[lane];

  // ---- prologue: times, y0, first outputs, noise ring ----
  for (int j = t; j < 512; j += 128) tl_s[j] = ts[j * 3];
  __syncthreads();
  for (int j = t; j < 511; j += 128) {
    float hh = tl_s[j + 1] - tl_s[j];
    hs_s[j] = hh;
    sq_s[j] = sqrtf(hh);
  }

  float y0v = 0.1f;
  if (lane < 3) y0v = fminf(fmaxf(ts[b * 1536 + lane], 0.01f), 10.f);
  y_s[w][lane] = y0v;
  float ymine = y0v;
  if (w == 0) out[(long)b * 32768 + lane] = y0v;
  else        outB[((long)b * 512) * 64 + lane] = f2b(y0v);

  const long nofs = (long)b * 64 + lane;
  float nz0 = noise[nofs];
  float nz1 = noise[4096 + nofs];
  float nz2 = noise[2 * 4096 + nofs];
  float nz3 = noise[3 * 4096 + nofs];
  __syncthreads();

  float* my_y = y_s[w];
  float* h1p  = h1s[w];

  for (int i = 0; i < 511; i++) {
    const int buf = i & 1;
    const float tl = tl_s[i];
    const float hh = hs_s[i];
    const float sq = sq_s[i];

    // noise shift-register (compile-time slot indices)
    const float nz = nz0;
    nz0 = nz1; nz1 = nz2; nz2 = nz3;
    if (i + 4 < 511) nz3 = noise[(long)(i + 4) * 4096 + nofs];

    // ---- stage A: 2 outputs/lane, broadcast y reads (own copy) ----
    float a00 = 0.f, a01 = 0.f, a10 = 0.f, a11 = 0.f;
#pragma unroll
    for (int g = 0; g < 16; g++) {
      float4 yv = *(const float4*)&my_y[g * 4];
      a00 += yv.x * wa0[g * 4 + 0]; a01 += yv.y * wa0[g * 4 + 1];
      a00 += yv.z * wa0[g * 4 + 2]; a01 += yv.w * wa0[g * 4 + 3];
      a10 += yv.x * wa1[g * 4 + 0]; a11 += yv.y * wa1[g * 4 + 1];
      a10 += yv.z * wa1[g * 4 + 2]; a11 += yv.w * wa1[g * 4 + 3];
    }
    float p0 = (a00 + a01) + tl * wt0 + bA0;
    float p1 = (a10 + a11) + tl * wt1 + bA1;
    h1p[lane]      = fast_tanh(p0);
    h1p[64 + lane] = fast_tanh(p1);
    wait_lds();

    // ---- stage B: 1 output/lane from own 128-wide hidden ----
    float c0 = 0.f, c1 = 0.f, c2 = 0.f, c3 = 0.f;
#pragma unroll
    for (int g = 0; g < 32; g++) {
      float4 hv = *(const float4*)&h1p[g * 4];
      c0 += hv.x * wb[g * 4 + 0]; c1 += hv.y * wb[g * 4 + 1];
      c2 += hv.z * wb[g * 4 + 2]; c3 += hv.w * wb[g * 4 + 3];
    }
    float p2 = (c0 + c1) + (c2 + c3) + bB;
    if (w == 0) {
      h2s[buf][lane] = fast_tanh(p2);
    } else {
      gcs[buf][lane] =
          fmaxf(p2, 0.f) + __logf(1.f + __expf(-fabsf(p2))) + mind;
    }
    barrier_lds();                       // the ONE cross-wave sync per step

    // ---- stage C (redundant on both waves) + y update ----
    float d0 = 0.f, d1 = 0.f, d2 = 0.f, d3 = 0.f;
    const float* h2p = h2s[buf];
#pragma unroll
    for (int g = 0; g < 16; g++) {
      float4 hv = *(const float4*)&h2p[g * 4];
      d0 += hv.x * wc[g * 4 + 0]; d1 += hv.y * wc[g * 4 + 1];
      d2 += hv.z * wc[g * 4 + 2]; d3 += hv.w * wc[g * 4 + 3];
    }
    float dc = fminf(fmaxf((d0 + d1) + (d2 + d3) + bC, -maxd), maxd);
    float gc = gcs[buf][lane];
    float yo = ymine;
    float yn = yo + dc * yo * hh + gc * fminf(fmaxf(yo, -10.f), 10.f) * nz * sq;
    yn = fminf(fmaxf(yn, 0.01f), 10.f);
    my_y[lane] = yn;
    ymine = yn;
    wait_lds();                          // own-copy write visible to own wave
    if (w == 0) out[(long)b * 32768 + (i + 1) * 64 + lane] = yn;
    else        outB[((long)b * 512 + i + 1) * 64 + lane] = f2b(yn);
  }
}

// ---------------------------------------------------------------------------
__global__ __launch_bounds__(256) void prep_weights(
    const float* __restrict__ in_W, const float* __restrict__ Wq,
    const float* __restrict__ Wk, const float* __restrict__ Wv,
    const float* __restrict__ Wo, const float* __restrict__ fW1,
    const float* __restrict__ fW2,
    u16* __restrict__ inWt, u16* __restrict__ qkvWt, u16* __restrict__ Wot,
    u16* __restrict__ fW1t, u16* __restrict__ fW2t) {
  const int z = blockIdx.z, layer = blockIdx.y, tile = blockIdx.x;
  const float* src; u16* dst; int R, C, nl;
  switch (z) {
    case 0: src = in_W; dst = inWt; R = 64; C = 128; nl = 1; break;
    case 1: src = Wq + layer * 16384; dst = qkvWt + layer * 49152; R = 128; C = 128; nl = 4; break;
    case 2: src = Wk + layer * 16384; dst = qkvWt + layer * 49152 + 16384; R = 128; C = 128; nl = 4; break;
    case 3: src = Wv + layer * 16384; dst = qkvWt + layer * 49152 + 32768; R = 128; C = 128; nl = 4; break;
    case 4: src = Wo + layer * 16384; dst = Wot + layer * 16384; R = 128; C = 128; nl = 4; break;
    case 5: src = fW1 + layer * 65536; dst = fW1t + layer * 65536; R = 128; C = 512; nl = 4; break;
    default: src = fW2 + layer * 65536; dst = fW2t + layer * 65536; R = 512; C = 128; nl = 4; break;
  }
  const int nt = (R / 32) * (C / 32);
  if (layer >= nl || tile >= nt) return;
  const int tpr = C / 32;
  const int r0 = (tile / tpr) * 32, c0 = (tile % tpr) * 32;
  __shared__ float tl[32][33];
  const int tx = threadIdx.x & 31, ty = threadIdx.x >> 5;
#pragma unroll
  for (int p = 0; p < 4; p++)
    tl[ty + 8 * p][tx] = src[(long)(r0 + ty + 8 * p) * C + c0 + tx];
  __syncthreads();
#pragma unroll
  for (int p = 0; p < 4; p++)
    dst[(long)(c0 + ty + 8 * p) * R + r0 + tx] = f2b(tl[tx][ty + 8 * p]);
}

// ---------------------------------------------------------------------------
// bf16 MFMA GEMM. MODE 1: bf16+relu. MODE 3: bf16.
// ---------------------------------------------------------------------------
template <int MODE>
__global__ __launch_bounds__(256) void mfma_gemm(
    const u16* __restrict__ A, const u16* __restrict__ Bt,
    const float* __restrict__ bias, u16* __restrict__ outB, int K, int N) {
  __shared__ u16 As[128 * 40];
  __shared__ u16 Bs[64 * 40];
  const int t = threadIdx.x;
  const int nb = blockIdx.x * 64;
  const long mb = (long)blockIdx.y * 128;
  const int lane = t & 63, wave = t >> 6;
  const int wm = (wave >> 1) * 64, wn = (wave & 1) * 32;
  const int fr = lane & 15, quad = lane >> 4;

  f32x4 zero = {0.f, 0.f, 0.f, 0.f};
  f32x4 acc[4][2];
#pragma unroll
  for (int mi = 0; mi < 4; mi++)
#pragma unroll
    for (int ni = 0; ni < 2; ni++) acc[mi][ni] = zero;

  for (int k0 = 0; k0 < K; k0 += 32) {
#pragma unroll
    for (int p = 0; p < 2; p++) {
      int idx = t + p * 256, row = idx >> 2, seg = idx & 3;
      int4 v = *(const int4*)&A[(mb + row) * K + k0 + seg * 8];
      *(int4*)&As[row * 40 + seg * 8] = v;
    }
    {
      int row = t >> 2, seg = t & 3;
      int4 v = *(const int4*)&Bt[(long)(nb + row) * K + k0 + seg * 8];
      *(int4*)&Bs[row * 40 + seg * 8] = v;
    }
    __syncthreads();
    bf16x8 af[4], bfr[2];
#pragma unroll
    for (int mi = 0; mi < 4; mi++)
      af[mi] = *(const bf16x8*)&As[(wm + mi * 16 + fr) * 40 + quad * 8];
#pragma unroll
    for (int ni = 0; ni < 2; ni++)
      bfr[ni] = *(const bf16x8*)&Bs[(wn + ni * 16 + fr) * 40 + quad * 8];
#pragma unroll
    for (int mi = 0; mi < 4; mi++)
#pragma unroll
      for (int ni = 0; ni < 2; ni++)
        acc[mi][ni] = __builtin_amdgcn_mfma_f32_16x16x32_bf16(
            af[mi], bfr[ni], acc[mi][ni], 0, 0, 0);
    __syncthreads();
  }

#pragma unroll
  for (int mi = 0; mi < 4; mi++)
#pragma unroll
    for (int ni = 0; ni < 2; ni++) {
      int col = nb + wn + ni * 16 + fr;
      float bv = bias[col];
#pragma unroll
      for (int r = 0; r < 4; r++) {
        long row = mb + wm + mi * 16 + quad * 4 + r;
        float v = acc[mi][ni][r] + bv;
        if (MODE == 1) {
          outB[row * N + col] = f2b(fmaxf(v, 0.f));
        } else {
          outB[row * N + col] = f2b(v);
        }
      }
    }
}

// ---------------------------------------------------------------------------
// Fused GEMM + residual(bf16) + LayerNorm -> bf16. Tile 64x128, 512 blocks.
// ---------------------------------------------------------------------------
__global__ __launch_bounds__(256) void gemm_ln(
    const u16* __restrict__ A, const u16* __restrict__ Bt,
    const float* __restrict__ bias, const u16* __restrict__ resid,
    const float* __restrict__ gamma, const float* __restrict__ beta,
    u16* __restrict__ outB, int K) {
  __shared__ u16 As[64 * 40];
  __shared__ u16 Bs[128 * 40];
  __shared__ float s1[2][64], s2[2][64];
  const int t = threadIdx.x;
  const long mb = (long)blockIdx.x * 64;
  const int lane = t & 63, wave = t >> 6;
  const int wm = (wave >> 1) * 32, wn = (wave & 1) * 64;
  const int fr = lane & 15, quad = lane >> 4;

  f32x4 zero = {0.f, 0.f, 0.f, 0.f};
  f32x4 acc[2][4];
#pragma unroll
  for (int mi = 0; mi < 2; mi++)
#pragma unroll
    for (int ni = 0; ni < 4; ni++) acc[mi][ni] = zero;

  for (int k0 = 0; k0 < K; k0 += 32) {
    {
      int row = t >> 2, seg = t & 3;
      *(int4*)&As[row * 40 + seg * 8] =
          *(const int4*)&A[(mb + row) * K + k0 + seg * 8];
    }
#pragma unroll
    for (int p = 0; p < 2; p++) {
      int idx = t + p * 256, row = idx >> 2, seg = idx & 3;
      *(int4*)&Bs[row * 40 + seg * 8] =
          *(const int4*)&Bt[(long)row * K + k0 + seg * 8];
    }
    __syncthreads();
    bf16x8 af[2], bfr[4];
#pragma unroll
    for (int mi = 0; mi < 2; mi++)
      af[mi] = *(const bf16x8*)&As[(wm + mi * 16 + fr) * 40 + quad * 8];
#pragma unroll
    for (int ni = 0; ni < 4; ni++)
      bfr[ni] = *(const bf16x8*)&Bs[(wn + ni * 16 + fr) * 40 + quad * 8];
#pragma unroll
    for (int mi = 0; mi < 2; mi++)
#pragma unroll
      for (int ni = 0; ni < 4; ni++)
        acc[mi][ni] = __builtin_amdgcn_mfma_f32_16x16x32_bf16(
            af[mi], bfr[ni], acc[mi][ni], 0, 0, 0);
    __syncthreads();
  }

  float bv[4], gv[4], be[4];
#pragma unroll
  for (int ni = 0; ni < 4; ni++) {
    int col = wn + ni * 16 + fr;
    bv[ni] = bias[col];
    gv[ni] = gamma[col];
    be[ni] = beta[col];
  }

#pragma unroll
  for (int mi = 0; mi < 2; mi++) {
#pragma unroll
    for (int r = 0; r < 4; r++) {
      int rloc = wm + mi * 16 + quad * 4 + r;
      long row = mb + rloc;
      float s = 0.f, ss = 0.f;
#pragma unroll
      for (int ni = 0; ni < 4; ni++) {
        int col = wn + ni * 16 + fr;
        float v = acc[mi][ni][r] + bv[ni] + b2f(resid[row * DD + col]);
        acc[mi][ni][r] = v;
        s += v;
        ss += v * v;
      }
      s += __shfl_xor(s, 1); ss += __shfl_xor(ss, 1);
      s += __shfl_xor(s, 2); ss += __shfl_xor(ss, 2);
      s += __shfl_xor(s, 4); ss += __shfl_xor(ss, 4);
      s += __shfl_xor(s, 8); ss += __shfl_xor(ss, 8);
      if (fr == 0) {
        s1[wn >> 6][rloc] = s;
        s2[wn >> 6][rloc] = ss;
      }
    }
  }
  __syncthreads();

#pragma unroll
  for (int mi = 0; mi < 2; mi++) {
#pragma unroll
    for (int r = 0; r < 4; r++) {
      int rloc = wm + mi * 16 + quad * 4 + r;
      long row = mb + rloc;
      float sum = s1[0][rloc] + s1[1][rloc];
      float sumsq = s2[0][rloc] + s2[1][rloc];
      float mean = sum * (1.f / 128.f);
      float var = sumsq * (1.f / 128.f) - mean * mean;
      float rstd = rsqrtf(var + 1e-5f);
#pragma unroll
      for (int ni = 0; ni < 4; ni++) {
        int col = wn + ni * 16 + fr;
        float o = (acc[mi][ni][r] - mean) * rstd * gv[ni] + be[ni];
        outB[row * DD + col] = f2b(o);
      }
    }
  }
}

// ---------------------------------------------------------------------------
// Fused QKV-projection + flash attention. One block per (b,h), 512 blocks,
// 2 blocks/CU (64.3 KB LDS). Block computes its head's Q/K/V (512x16 each,
// K=128 — head slices exactly partition the QKV GEMM) into LDS, then runs
// the S^T-orientation online-softmax loop (verified round 8).
// ---------------------------------------------------------------------------
__global__ __launch_bounds__(256, 2) void qkv_attn(
    const u16* __restrict__ xb, const u16* __restrict__ qkvW,
    const float* __restrict__ bq, const float* __restrict__ bk,
    const float* __restrict__ bv, u16* __restrict__ Og) {
  const int bh = blockIdx.x;
  const int b = bh >> 3, h = bh & 7;
  __shared__ u16 Ks[512 * 24];     // [key][d]  (24 KB)
  __shared__ u16 Vt[16 * 520];     // [d][key]  (16.3 KB)
  __shared__ u16 Qs[512 * 24];     // [q][d]    (24 KB)
  const int t = threadIdx.x;
  const int w = t >> 6, lane = t & 63;
  const int fr = lane & 15, quad = lane >> 4;
  const long obase = ((long)b * SS) * DD + h * 16;
  const u16* xrow = xb + (long)b * SS * DD;

  // ---- head weight B-frags (register-resident) ----
  const u16* Wq_h = qkvW + (h * 16) * 128;
  const u16* Wk_h = qkvW + 16384 + (h * 16) * 128;
  const u16* Wv_h = qkvW + 32768 + (h * 16) * 128;
  bf16x8 wqf[4], wkf[4], wvf[4];
#pragma unroll
  for (int c = 0; c < 4; c++) {
    wqf[c] = *(const bf16x8*)&Wq_h[fr * 128 + c * 32 + quad * 8];
    wkf[c] = *(const bf16x8*)&Wk_h[fr * 128 + c * 32 + quad * 8];
    wvf[c] = *(const bf16x8*)&Wv_h[fr * 128 + c * 32 + quad * 8];
  }
  const float bqv = bq[h * 16 + fr];
  const float bkv = bk[h * 16 + fr];
  const float bvv = bv[h * 16 + fr];
  const f32x4 z4 = {0.f, 0.f, 0.f, 0.f};

  // ---- project Q/K/V for this head into LDS ----
  for (int tile = w; tile < 32; tile += 4) {
    const int t0 = tile * 16;
    bf16x8 af[4];
#pragma unroll
    for (int c = 0; c < 4; c++)
      af[c] = *(const bf16x8*)&xrow[(t0 + fr) * 128 + c * 32 + quad * 8];
    f32x4 qa = z4, ka = z4, va = z4;
#pragma unroll
    for (int c = 0; c < 4; c++) {
      qa = __builtin_amdgcn_mfma_f32_16x16x32_bf16(af[c], wqf[c], qa, 0, 0, 0);
      ka = __builtin_amdgcn_mfma_f32_16x16x32_bf16(af[c], wkf[c], ka, 0, 0, 0);
      va = __builtin_amdgcn_mfma_f32_16x16x32_bf16(af[c], wvf[c], va, 0, 0, 0);
    }
    // C-layout: lane holds (d = fr, row = t0 + quad*4 + r)
#pragma unroll
    for (int r = 0; r < 4; r++) {
      int row = t0 + quad * 4 + r;
      Qs[row * 24 + fr] = f2b(qa[r] + bqv);
      Ks[row * 24 + fr] = f2b(ka[r] + bkv);
      Vt[fr * 520 + row] = f2b(va[r] + bvv);
    }
  }
  __syncthreads();

  // ---- flash attention (S^T orientation) ----
  const float scale = 0.25f;                 // 1/sqrt(16)
  const int addrA = (((quad & 1) * 32) + fr) * 4;
  const int addrB = addrA + 64;
  const bool loTile = (quad < 2);

  for (int qt = w; qt < 32; qt += 4) {
    const int q0 = qt * 16;
    bf16x8 qf = {0, 0, 0, 0, 0, 0, 0, 0};
    if (quad < 2)
      qf = *(const bf16x8*)&Qs[(q0 + fr) * 24 + quad * 8];
    f32x4 oacc = {0.f, 0.f, 0.f, 0.f};
    float mrun = -1e30f, lrun = 0.f;

    for (int kt = 0; kt < 16; kt++) {
      const int k0 = kt * 32;
      bf16x8 kf0 = {0, 0, 0, 0, 0, 0, 0, 0};
      bf16x8 kf1 = {0, 0, 0, 0, 0, 0, 0, 0};
      if (quad < 2) {
        kf0 = *(const bf16x8*)&Ks[(k0 + fr) * 24 + quad * 8];
        kf1 = *(const bf16x8*)&Ks[(k0 + 16 + fr) * 24 + quad * 8];
      }
      f32x4 slo = __builtin_amdgcn_mfma_f32_16x16x32_bf16(kf0, qf, z4, 0, 0, 0);
      f32x4 shi = __builtin_amdgcn_mfma_f32_16x16x32_bf16(kf1, qf, z4, 0, 0, 0);
      float s[8];
#pragma unroll
      for (int r = 0; r < 4; r++) {
        s[r] = slo[r] * scale;
        s[4 + r] = shi[r] * scale;
      }
      float mx = s[0];
#pragma unroll
      for (int r = 1; r < 8; r++) mx = fmaxf(mx, s[r]);
      mx = fmaxf(mx, __shfl_xor(mx, 16));
      mx = fmaxf(mx, __shfl_xor(mx, 32));
      float nm = fmaxf(mrun, mx);
      float alpha = __expf(mrun - nm);
      mrun = nm;
      float p[8], rs = 0.f;
#pragma unroll
      for (int r = 0; r < 8; r++) {
        p[r] = __expf(s[r] - nm);
        rs += p[r];
      }
      rs += __shfl_xor(rs, 16);
      rs += __shfl_xor(rs, 32);
      lrun = lrun * alpha + rs;
#pragma unroll
      for (int r = 0; r < 4; r++) oacc[r] *= alpha;

      int pk0 = ((int)f2b(p[1]) << 16) | f2b(p[0]);
      int pk1 = ((int)f2b(p[3]) << 16) | f2b(p[2]);
      int pk2 = ((int)f2b(p[5]) << 16) | f2b(p[4]);
      int pk3 = ((int)f2b(p[7]) << 16) | f2b(p[6]);
      int B0a = __builtin_amdgcn_ds_bpermute(addrA, pk0);
      int B0b = __builtin_amdgcn_ds_bpermute(addrA, pk2);
      int B1a = __builtin_amdgcn_ds_bpermute(addrA, pk1);
      int B1b = __builtin_amdgcn_ds_bpermute(addrA, pk3);
      int B2a = __builtin_amdgcn_ds_bpermute(addrB, pk0);
      int B2b = __builtin_amdgcn_ds_bpermute(addrB, pk2);
      int B3a = __builtin_amdgcn_ds_bpermute(addrB, pk1);
      int B3b = __builtin_amdgcn_ds_bpermute(addrB, pk3);
      union { int i[4]; bf16x8 v; } pu;
      pu.i[0] = loTile ? B0a : B0b;
      pu.i[1] = loTile ? B1a : B1b;
      pu.i[2] = loTile ? B2a : B2b;
      pu.i[3] = loTile ? B3a : B3b;
      bf16x8 vf = *(const bf16x8*)&Vt[fr * 520 + k0 + quad * 8];
      oacc = __builtin_amdgcn_mfma_f32_16x16x32_bf16(vf, pu.v, oacc, 0, 0, 0);
    }

    float inv = __fdividef(1.f, lrun);
    ushort4 o;
    o.x = f2b(oacc[0] * inv);
    o.y = f2b(oacc[1] * inv);
    o.z = f2b(oacc[2] * inv);
    o.w = f2b(oacc[3] * inv);
    *(ushort4*)&Og[obase + (long)(q0 + fr) * DD + quad * 4] = o;
  }
}

// ---------------------------------------------------------------------------
__global__ __launch_bounds__(128) void pool_kernel(const u16* __restrict__ X,
                                                   float* __restrict__ P) {
  const int b = blockIdx.x, c = threadIdx.x;
  float acc = 0.f;
  for (int s = 0; s < SS; s++) acc += b2f(X[((long)b * SS + s) * DD + c]);
  P[b * DD + c] = acc * (1.f / 512.f);
}

__global__ __launch_bounds__(64) void cls_kernel(
    const float* __restrict__ P, const float* __restrict__ W1,
    const float* __restrict__ b1, const float* __restrict__ W2,
    const float* __restrict__ b2, float* __restrict__ L) {
  const int b = blockIdx.x, t = threadIdx.x;
  __shared__ float sp[128];
  __shared__ float sh[64];
  sp[t] = P[b * DD + t];
  sp[t + 64] = P[b * DD + 64 + t];
  __syncthreads();
  float acc = b1[t];
  for (int k = 0; k < 128; k++) acc += sp[k] * W1[k * 64 + t];
  sh[t] = fmaxf(acc, 0.f);
  __syncthreads();
  if (t < 5) {
    float acc2 = b2[t];
    for (int k = 0; k < 64; k++) acc2 += sh[k] * W2[k * 5 + t];
    L[b * 5 + t] = acc2;
  }
}

// ---------------------------------------------------------------------------
extern "C" void kernel_launch(void* const* d_in, const int* in_sizes, int n_in,
                              void* d_out, int out_size, void* d_ws, size_t ws_size,
                              hipStream_t stream) {
  const float* ts    = (const float*)d_in[0];
  const float* noise = (const float*)d_in[2];
  const float* dW1   = (const float*)d_in[3];
  const float* db1   = (const float*)d_in[4];
  const float* dW2   = (const float*)d_in[5];
  const float* db2   = (const float*)d_in[6];
  const float* dW3   = (const float*)d_in[7];
  const float* db3   = (const float*)d_in[8];
  const float* gW1   = (const float*)d_in[9];
  const float* gb1   = (const float*)d_in[10];
  const float* gW2   = (const float*)d_in[11];
  const float* gb2   = (const float*)d_in[12];
  const float* mind  = (const float*)d_in[13];
  const float* maxd  = (const float*)d_in[14];
  const float* in_W  = (const float*)d_in[15];
  const float* in_b  = (const float*)d_in[16];
  const float* Wq    = (const float*)d_in[17];
  const float* bq    = (const float*)d_in[18];
  const float* Wk    = (const float*)d_in[19];
  const float* bk    = (const float*)d_in[20];
  const float* Wv    = (const float*)d_in[21];
  const float* bv    = (const float*)d_in[22];
  const float* Wo    = (const float*)d_in[23];
  const float* bo    = (const float*)d_in[24];
  const float* ln1s  = (const float*)d_in[25];
  const float* ln1b  = (const float*)d_in[26];
  const float* fW1   = (const float*)d_in[27];
  const float* fb1   = (const float*)d_in[28];
  const float* fW2   = (const float*)d_in[29];
  const float* fb2   = (const float*)d_in[30];
  const float* ln2s  = (const float*)d_in[31];
  const float* ln2b  = (const float*)d_in[32];
  const float* cW1   = (const float*)d_in[33];
  const float* cb1   = (const float*)d_in[34];
  const float* cW2   = (const float*)d_in[35];
  const float* cb2   = (const float*)d_in[36];

  float* logits = (float*)d_out;
  float* sde    = logits + BB * 5;

  // Workspace (all-bf16 residual stream):
  char* W = (char*)d_ws;
  u16*  bxb    = (u16*)(W);                   //  8 MB bf16 x
  u16*  bh     = (u16*)(W + (8u << 20));      // 32 MB FFN hidden
  u16*  bob    = (u16*)(W + (40u << 20));     //  8 MB bf16 attn out
  u16*  bsb    = (u16*)(W + (48u << 20));     //  4 MB bf16 sde feats
  u16*  wts    = (u16*)(W + (52u << 20));     // ~1.5 MB bf16 weights
  float* bp    = (float*)(W + (54u << 20));   // pooled 64x128

  u16* inWt  = wts;                 // [128][64]
  u16* qkvWt = inWt + 8192;         // [4][3][128][128]
  u16* Wot   = qkvWt + 196608;      // [4][128][128]
  u16* fW1t  = Wot + 65536;         // [4][512][128]
  u16* fW2t  = fW1t + 262144;       // [4][128][512]

  prep_weights<<<dim3(64, 4, 7), 256, 0, stream>>>(in_W, Wq, Wk, Wv, Wo, fW1, fW2,
                                                   inWt, qkvWt, Wot, fW1t, fW2t);

  sde_kernel<<<64, 128, 0, stream>>>(ts, noise, dW1, db1, dW2, db2, dW3, db3,
                                     gW1, gb1, gW2, gb2, mind, maxd, sde, bsb);

  // x = sde @ in_W + in_b  (bf16)
  mfma_gemm<3><<<dim3(2, 256), 256, 0, stream>>>(bsb, inWt, in_b, bxb, 64, 128);

  for (int l = 0; l < 4; l++) {
    qkv_attn<<<BB * NHD, 256, 0, stream>>>(bxb, qkvWt + l * 49152,
                                           bq + l * DD, bk + l * DD, bv + l * DD,
                                           bob);
    gemm_ln<<<512, 256, 0, stream>>>(bob, Wot + l * 16384, bo + l * DD, bxb,
                                     ln1s + l * DD, ln1b + l * DD, bxb, 128);
    mfma_gemm<1><<<dim3(8, 256), 256, 0, stream>>>(bxb, fW1t + l * 65536,
                                                   fb1 + l * 512, bh, 128, 512);
    gemm_ln<<<512, 256, 0, stream>>>(bh, fW2t + l * 65536, fb2 + l * DD, bxb,
                                     ln2s + l * DD, ln2b + l * DD, bxb, 512);
  }

  pool_kernel<<<BB, 128, 0, stream>>>(bxb, bp);
  cls_kernel<<<BB, 64, 0, stream>>>(bp, cW1, cb1, cW2, cb2, logits);
}

// Round 2
// 1331.980 us; speedup vs baseline: 1.5424x; 1.5424x over previous
//
#include <hip/hip_runtime.h>
#include <hip/hip_bf16.h>
#include <math.h>

#define BB 64
#define SS 512
#define HH 64
#define DD 128
#define NHD 8
#define ROWS (BB*SS)   // 32768

typedef unsigned short u16;
typedef __attribute__((ext_vector_type(8))) short bf16x8;
typedef __attribute__((ext_vector_type(4))) float f32x4;

__device__ __forceinline__ u16 f2b(float f) {
  union { float f; unsigned u; } x; x.f = f;
  unsigned r = x.u + 0x7fffu + ((x.u >> 16) & 1u);
  return (u16)(r >> 16);
}

__device__ __forceinline__ float b2f(u16 u) {
  return __uint_as_float(((unsigned)u) << 16);
}

__device__ __forceinline__ float fast_tanh(float x) {
  float ax = fminf(fabsf(x), 15.f);
  float e = __expf(2.f * ax);
  float r = 1.f - __fdividef(2.f, e + 1.f);
  return copysignf(r, x);
}

__device__ __forceinline__ void barrier_lds() {
  __builtin_amdgcn_s_waitcnt(0xC07F);   // lgkmcnt(0) only
  __builtin_amdgcn_s_barrier();
}

// ---------------------------------------------------------------------------
// SDE scan v8: 256 threads (4 waves), same verified 3-barrier structure as
// v6 but with per-SIMD-invariant issue spread over fewer, fatter threads:
// stage A 1-way (1 out/thread, 65 MACs, no shuffle), B 2-way (64 MACs,
// 1 shfl), C 4-way (16 MACs, 2 shfl). 145 weight floats/lane live in
// straight VGPRs (4-wave block = 1 wave/SIMD -> 512-reg budget, no spill,
// no AGPR round-trips). qC==0 threads carry y[cC] in a register across
// steps. All LDS read patterns are broadcast or 2-way bank-aliased (free).
// ---------------------------------------------------------------------------
__global__ __launch_bounds__(256) void sde_kernel(
    const float* __restrict__ ts, const float* __restrict__ noise,
    const float* __restrict__ dW1, const float* __restrict__ db1,
    const float* __restrict__ dW2, const float* __restrict__ db2,
    const float* __restrict__ dW3, const float* __restrict__ db3,
    const float* __restrict__ gW1, const float* __restrict__ gb1,
    const float* __restrict__ gW2, const float* __restrict__ gb2,
    const float* __restrict__ pmind, const float* __restrict__ pmaxd,
    float* __restrict__ out, u16* __restrict__ outB) {
  const int b = blockIdx.x, t = threadIdx.x;
  __shared__ float y_s[64];
  __shared__ float h1s[256];
  __shared__ float h2s[64], gcs[64];
  __shared__ float tl_s[512], hs_s[512], sq_s[512];

  const float mind = fabsf(pmind[0]);
  const float maxd = fabsf(pmaxd[0]);

  // ---- stage A weights: one output column per thread ----
  const int cA = t & 127;
  const float* W1 = (t < 128) ? dW1 : gW1;
  float wA[64];
#pragma unroll
  for (int k = 0; k < 64; k++) wA[k] = W1[k * 128 + cA];
  const float wAt = W1[64 * 128 + cA];
  const float bA = ((t < 128) ? db1 : gb1)[cA];

  // ---- stage B weights: 2 threads per output ----
  const int oB = t >> 1, hB = t & 1;
  const int cB = oB & 63;
  const float* W2 = (oB < 64) ? dW2 : gW2;
  float wB[64];
#pragma unroll
  for (int k = 0; k < 64; k++) wB[k] = W2[(hB * 64 + k) * 64 + cB];
  const float bB = ((oB < 64) ? db2 : gb2)[cB];

  // ---- stage C weights: 4 threads per output ----
  const int cC = t >> 2, qC = t & 3;
  float wC[16];
#pragma unroll
  for (int k = 0; k < 16; k++) wC[k] = dW3[(qC * 16 + k) * 64 + cC];
  const float bC = db3[cC];

  // ---- prologue ----
  for (int j = t; j < 512; j += 256) tl_s[j] = ts[j * 3];
  __syncthreads();
  for (int j = t; j < 511; j += 256) {
    float hh = tl_s[j + 1] - tl_s[j];
    hs_s[j] = hh;
    sq_s[j] = sqrtf(hh);
  }

  // y0 for my owned column (all threads compute; only qC==0 uses ymine)
  float ymine = 0.1f;
  if (cC < 3) ymine = fminf(fmaxf(ts[b * 1536 + cC], 0.01f), 10.f);
  if (t < 64) {
    float y = 0.1f;
    if (t < 3) y = fminf(fmaxf(ts[b * 1536 + t], 0.01f), 10.f);
    y_s[t] = y;
    out[(long)b * 32768 + t] = y;
    outB[((long)b * 512) * 64 + t] = f2b(y);
  }
  float nz = noise[(long)b * 64 + cC];
  __syncthreads();

  for (int i = 0; i < 511; i++) {
    float nzn = 0.f;
    if (i < 510) nzn = noise[(long)(i + 1) * 4096 + b * 64 + cC];
    const float tl = tl_s[i];
    const float hh = hs_s[i];
    const float sq = sq_s[i];

    // ---- stage A: 1 out/thread, 65 MACs, broadcast y reads ----
    float a0 = 0.f, a1 = 0.f, a2 = 0.f, a3 = 0.f;
#pragma unroll
    for (int g = 0; g < 16; g++) {
      float4 yv = *(const float4*)&y_s[g * 4];
      a0 += yv.x * wA[g * 4 + 0];
      a1 += yv.y * wA[g * 4 + 1];
      a2 += yv.z * wA[g * 4 + 2];
      a3 += yv.w * wA[g * 4 + 3];
    }
    float p1 = (a0 + a1) + (a2 + a3) + tl * wAt + bA;
    h1s[t] = fast_tanh(p1);
    barrier_lds();                        // barrier 1

    // ---- stage B: 2 thr/out, 64 MACs, 1 shfl ----
    const float* srcB = h1s + ((oB < 64) ? 0 : 128) + hB * 64;
    float c0 = 0.f, c1 = 0.f, c2 = 0.f, c3 = 0.f;
#pragma unroll
    for (int g = 0; g < 16; g++) {
      float4 xv = *(const float4*)&srcB[g * 4];
      c0 += xv.x * wB[g * 4 + 0];
      c1 += xv.y * wB[g * 4 + 1];
      c2 += xv.z * wB[g * 4 + 2];
      c3 += xv.w * wB[g * 4 + 3];
    }
    float p2 = (c0 + c1) + (c2 + c3);
    p2 += __shfl_xor(p2, 1);
    if (hB == 0) {
      p2 += bB;
      if (oB < 64) {
        h2s[cB] = fast_tanh(p2);
      } else {
        gcs[cB] = fmaxf(p2, 0.f) + __logf(1.f + __expf(-fabsf(p2))) + mind;
      }
    }
    barrier_lds();                        // barrier 2

    // ---- stage C: 4 thr/out, 16 MACs, 2 shfl ----
    float d0 = 0.f, d1 = 0.f, d2 = 0.f, d3 = 0.f;
#pragma unroll
    for (int g = 0; g < 4; g++) {
      float4 hv = *(const float4*)&h2s[qC * 16 + g * 4];
      d0 += hv.x * wC[g * 4 + 0];
      d1 += hv.y * wC[g * 4 + 1];
      d2 += hv.z * wC[g * 4 + 2];
      d3 += hv.w * wC[g * 4 + 3];
    }
    float p3 = (d0 + d1) + (d2 + d3);
    p3 += __shfl_xor(p3, 1);
    p3 += __shfl_xor(p3, 2);
    if (qC == 0) {
      float dc = fminf(fmaxf(p3 + bC, -maxd), maxd);
      float gg = gcs[cC] * fminf(fmaxf(ymine, -10.f), 10.f);
      float yn = ymine + dc * ymine * hh + gg * nz * sq;
      yn = fminf(fmaxf(yn, 0.01f), 10.f);
      y_s[cC] = yn;
      ymine = yn;
      out[(long)b * 32768 + (i + 1) * 64 + cC] = yn;
      outB[((long)b * 512 + i + 1) * 64 + cC] = f2b(yn);
    }
    nz = nzn;
    barrier_lds();                        // barrier 3
  }
}

// ---------------------------------------------------------------------------
__global__ __launch_bounds__(256) void prep_weights(
    const float* __restrict__ in_W, const float* __restrict__ Wq,
    const float* __restrict__ Wk, const float* __restrict__ Wv,
    const float* __restrict__ Wo, const float* __restrict__ fW1,
    const float* __restrict__ fW2,
    u16* __restrict__ inWt, u16* __restrict__ qkvWt, u16* __restrict__ Wot,
    u16* __restrict__ fW1t, u16* __restrict__ fW2t) {
  const int z = blockIdx.z, layer = blockIdx.y, tile = blockIdx.x;
  const float* src; u16* dst; int R, C, nl;
  switch (z) {
    case 0: src = in_W; dst = inWt; R = 64; C = 128; nl = 1; break;
    case 1: src = Wq + layer * 16384; dst = qkvWt + layer * 49152; R = 128; C = 128; nl = 4; break;
    case 2: src = Wk + layer * 16384; dst = qkvWt + layer * 49152 + 16384; R = 128; C = 128; nl = 4; break;
    case 3: src = Wv + layer * 16384; dst = qkvWt + layer * 49152 + 32768; R = 128; C = 128; nl = 4; break;
    case 4: src = Wo + layer * 16384; dst = Wot + layer * 16384; R = 128; C = 128; nl = 4; break;
    case 5: src = fW1 + layer * 65536; dst = fW1t + layer * 65536; R = 128; C = 512; nl = 4; break;
    default: src = fW2 + layer * 65536; dst = fW2t + layer * 65536; R = 512; C = 128; nl = 4; break;
  }
  const int nt = (R / 32) * (C / 32);
  if (layer >= nl || tile >= nt) return;
  const int tpr = C / 32;
  const int r0 = (tile / tpr) * 32, c0 = (tile % tpr) * 32;
  __shared__ float tl[32][33];
  const int tx = threadIdx.x & 31, ty = threadIdx.x >> 5;
#pragma unroll
  for (int p = 0; p < 4; p++)
    tl[ty + 8 * p][tx] = src[(long)(r0 + ty + 8 * p) * C + c0 + tx];
  __syncthreads();
#pragma unroll
  for (int p = 0; p < 4; p++)
    dst[(long)(c0 + ty + 8 * p) * R + r0 + tx] = f2b(tl[tx][ty + 8 * p]);
}

// ---------------------------------------------------------------------------
// bf16 MFMA GEMM. MODE 1: bf16+relu. MODE 3: bf16.
// ---------------------------------------------------------------------------
template <int MODE>
__global__ __launch_bounds__(256) void mfma_gemm(
    const u16* __restrict__ A, const u16* __restrict__ Bt,
    const float* __restrict__ bias, u16* __restrict__ outB, int K, int N) {
  __shared__ u16 As[128 * 40];
  __shared__ u16 Bs[64 * 40];
  const int t = threadIdx.x;
  const int nb = blockIdx.x * 64;
  const long mb = (long)blockIdx.y * 128;
  const int lane = t & 63, wave = t >> 6;
  const int wm = (wave >> 1) * 64, wn = (wave & 1) * 32;
  const int fr = lane & 15, quad = lane >> 4;

  f32x4 zero = {0.f, 0.f, 0.f, 0.f};
  f32x4 acc[4][2];
#pragma unroll
  for (int mi = 0; mi < 4; mi++)
#pragma unroll
    for (int ni = 0; ni < 2; ni++) acc[mi][ni] = zero;

  for (int k0 = 0; k0 < K; k0 += 32) {
#pragma unroll
    for (int p = 0; p < 2; p++) {
      int idx = t + p * 256, row = idx >> 2, seg = idx & 3;
      int4 v = *(const int4*)&A[(mb + row) * K + k0 + seg * 8];
      *(int4*)&As[row * 40 + seg * 8] = v;
    }
    {
      int row = t >> 2, seg = t & 3;
      int4 v = *(const int4*)&Bt[(long)(nb + row) * K + k0 + seg * 8];
      *(int4*)&Bs[row * 40 + seg * 8] = v;
    }
    __syncthreads();
    bf16x8 af[4], bfr[2];
#pragma unroll
    for (int mi = 0; mi < 4; mi++)
      af[mi] = *(const bf16x8*)&As[(wm + mi * 16 + fr) * 40 + quad * 8];
#pragma unroll
    for (int ni = 0; ni < 2; ni++)
      bfr[ni] = *(const bf16x8*)&Bs[(wn + ni * 16 + fr) * 40 + quad * 8];
#pragma unroll
    for (int mi = 0; mi < 4; mi++)
#pragma unroll
      for (int ni = 0; ni < 2; ni++)
        acc[mi][ni] = __builtin_amdgcn_mfma_f32_16x16x32_bf16(
            af[mi], bfr[ni], acc[mi][ni], 0, 0, 0);
    __syncthreads();
  }

#pragma unroll
  for (int mi = 0; mi < 4; mi++)
#pragma unroll
    for (int ni = 0; ni < 2; ni++) {
      int col = nb + wn + ni * 16 + fr;
      float bv = bias[col];
#pragma unroll
      for (int r = 0; r < 4; r++) {
        long row = mb + wm + mi * 16 + quad * 4 + r;
        float v = acc[mi][ni][r] + bv;
        if (MODE == 1) {
          outB[row * N + col] = f2b(fmaxf(v, 0.f));
        } else {
          outB[row * N + col] = f2b(v);
        }
      }
    }
}

// ---------------------------------------------------------------------------
// Fused GEMM + residual(bf16) + LayerNorm -> bf16. Tile 64x128, 512 blocks.
// ---------------------------------------------------------------------------
__global__ __launch_bounds__(256) void gemm_ln(
    const u16* __restrict__ A, const u16* __restrict__ Bt,
    const float* __restrict__ bias, const u16* __restrict__ resid,
    const float* __restrict__ gamma, const float* __restrict__ beta,
    u16* __restrict__ outB, int K) {
  __shared__ u16 As[64 * 40];
  __shared__ u16 Bs[128 * 40];
  __shared__ float s1[2][64], s2[2][64];
  const int t = threadIdx.x;
  const long mb = (long)blockIdx.x * 64;
  const int lane = t & 63, wave = t >> 6;
  const int wm = (wave >> 1) * 32, wn = (wave & 1) * 64;
  const int fr = lane & 15, quad = lane >> 4;

  f32x4 zero = {0.f, 0.f, 0.f, 0.f};
  f32x4 acc[2][4];
#pragma unroll
  for (int mi = 0; mi < 2; mi++)
#pragma unroll
    for (int ni = 0; ni < 4; ni++) acc[mi][ni] = zero;

  for (int k0 = 0; k0 < K; k0 += 32) {
    {
      int row = t >> 2, seg = t & 3;
      *(int4*)&As[row * 40 + seg * 8] =
          *(const int4*)&A[(mb + row) * K + k0 + seg * 8];
    }
#pragma unroll
    for (int p = 0; p < 2; p++) {
      int idx = t + p * 256, row = idx >> 2, seg = idx & 3;
      *(int4*)&Bs[row * 40 + seg * 8] =
          *(const int4*)&Bt[(long)row * K + k0 + seg * 8];
    }
    __syncthreads();
    bf16x8 af[2], bfr[4];
#pragma unroll
    for (int mi = 0; mi < 2; mi++)
      af[mi] = *(const bf16x8*)&As[(wm + mi * 16 + fr) * 40 + quad * 8];
#pragma unroll
    for (int ni = 0; ni < 4; ni++)
      bfr[ni] = *(const bf16x8*)&Bs[(wn + ni * 16 + fr) * 40 + quad * 8];
#pragma unroll
    for (int mi = 0; mi < 2; mi++)
#pragma unroll
      for (int ni = 0; ni < 4; ni++)
        acc[mi][ni] = __builtin_amdgcn_mfma_f32_16x16x32_bf16(
            af[mi], bfr[ni], acc[mi][ni], 0, 0, 0);
    __syncthreads();
  }

  float bv[4], gv[4], be[4];
#pragma unroll
  for (int ni = 0; ni < 4; ni++) {
    int col = wn + ni * 16 + fr;
    bv[ni] = bias[col];
    gv[ni] = gamma[col];
    be[ni] = beta[col];
  }

#pragma unroll
  for (int mi = 0; mi < 2; mi++) {
#pragma unroll
    for (int r = 0; r < 4; r++) {
      int rloc = wm + mi * 16 + quad * 4 + r;
      long row = mb + rloc;
      float s = 0.f, ss = 0.f;
#pragma unroll
      for (int ni = 0; ni < 4; ni++) {
        int col = wn + ni * 16 + fr;
        float v = acc[mi][ni][r] + bv[ni] + b2f(resid[row * DD + col]);
        acc[mi][ni][r] = v;
        s += v;
        ss += v * v;
      }
      s += __shfl_xor(s, 1); ss += __shfl_xor(ss, 1);
      s += __shfl_xor(s, 2); ss += __shfl_xor(ss, 2);
      s += __shfl_xor(s, 4); ss += __shfl_xor(ss, 4);
      s += __shfl_xor(s, 8); ss += __shfl_xor(ss, 8);
      if (fr == 0) {
        s1[wn >> 6][rloc] = s;
        s2[wn >> 6][rloc] = ss;
      }
    }
  }
  __syncthreads();

#pragma unroll
  for (int mi = 0; mi < 2; mi++) {
#pragma unroll
    for (int r = 0; r < 4; r++) {
      int rloc = wm + mi * 16 + quad * 4 + r;
      long row = mb + rloc;
      float sum = s1[0][rloc] + s1[1][rloc];
      float sumsq = s2[0][rloc] + s2[1][rloc];
      float mean = sum * (1.f / 128.f);
      float var = sumsq * (1.f / 128.f) - mean * mean;
      float rstd = rsqrtf(var + 1e-5f);
#pragma unroll
      for (int ni = 0; ni < 4; ni++) {
        int col = wn + ni * 16 + fr;
        float o = (acc[mi][ni][r] - mean) * rstd * gv[ni] + be[ni];
        outB[row * DD + col] = f2b(o);
      }
    }
  }
}

// ---------------------------------------------------------------------------
// Fused QKV-projection + flash attention. One block per (b,h), 512 blocks,
// 2 blocks/CU (64.3 KB LDS). Block computes its head's Q/K/V (512x16 each,
// K=128 — head slices exactly partition the QKV GEMM) into LDS, then runs
// the S^T-orientation online-softmax loop (verified round 8).
// ---------------------------------------------------------------------------
__global__ __launch_bounds__(256, 2) void qkv_attn(
    const u16* __restrict__ xb, const u16* __restrict__ qkvW,
    const float* __restrict__ bq, const float* __restrict__ bk,
    const float* __restrict__ bv, u16* __restrict__ Og) {
  const int bh = blockIdx.x;
  const int b = bh >> 3, h = bh & 7;
  __shared__ u16 Ks[512 * 24];     // [key][d]  (24 KB)
  __shared__ u16 Vt[16 * 520];     // [d][key]  (16.3 KB)
  __shared__ u16 Qs[512 * 24];     // [q][d]    (24 KB)
  const int t = threadIdx.x;
  const int w = t >> 6, lane = t & 63;
  const int fr = lane & 15, quad = lane >> 4;
  const long obase = ((long)b * SS) * DD + h * 16;
  const u16* xrow = xb + (long)b * SS * DD;

  // ---- head weight B-frags (register-resident) ----
  const u16* Wq_h = qkvW + (h * 16) * 128;
  const u16* Wk_h = qkvW + 16384 + (h * 16) * 128;
  const u16* Wv_h = qkvW + 32768 + (h * 16) * 128;
  bf16x8 wqf[4], wkf[4], wvf[4];
#pragma unroll
  for (int c = 0; c < 4; c++) {
    wqf[c] = *(const bf16x8*)&Wq_h[fr * 128 + c * 32 + quad * 8];
    wkf[c] = *(const bf16x8*)&Wk_h[fr * 128 + c * 32 + quad * 8];
    wvf[c] = *(const bf16x8*)&Wv_h[fr * 128 + c * 32 + quad * 8];
  }
  const float bqv = bq[h * 16 + fr];
  const float bkv = bk[h * 16 + fr];
  const float bvv = bv[h * 16 + fr];
  const f32x4 z4 = {0.f, 0.f, 0.f, 0.f};

  // ---- project Q/K/V for this head into LDS ----
  for (int tile = w; tile < 32; tile += 4) {
    const int t0 = tile * 16;
    bf16x8 af[4];
#pragma unroll
    for (int c = 0; c < 4; c++)
      af[c] = *(const bf16x8*)&xrow[(t0 + fr) * 128 + c * 32 + quad * 8];
    f32x4 qa = z4, ka = z4, va = z4;
#pragma unroll
    for (int c = 0; c < 4; c++) {
      qa = __builtin_amdgcn_mfma_f32_16x16x32_bf16(af[c], wqf[c], qa, 0, 0, 0);
      ka = __builtin_amdgcn_mfma_f32_16x16x32_bf16(af[c], wkf[c], ka, 0, 0, 0);
      va = __builtin_amdgcn_mfma_f32_16x16x32_bf16(af[c], wvf[c], va, 0, 0, 0);
    }
    // C-layout: lane holds (d = fr, row = t0 + quad*4 + r)
#pragma unroll
    for (int r = 0; r < 4; r++) {
      int row = t0 + quad * 4 + r;
      Qs[row * 24 + fr] = f2b(qa[r] + bqv);
      Ks[row * 24 + fr] = f2b(ka[r] + bkv);
      Vt[fr * 520 + row] = f2b(va[r] + bvv);
    }
  }
  __syncthreads();

  // ---- flash attention (S^T orientation) ----
  const float scale = 0.25f;                 // 1/sqrt(16)
  const int addrA = (((quad & 1) * 32) + fr) * 4;
  const int addrB = addrA + 64;
  const bool loTile = (quad < 2);

  for (int qt = w; qt < 32; qt += 4) {
    const int q0 = qt * 16;
    bf16x8 qf = {0, 0, 0, 0, 0, 0, 0, 0};
    if (quad < 2)
      qf = *(const bf16x8*)&Qs[(q0 + fr) * 24 + quad * 8];
    f32x4 oacc = {0.f, 0.f, 0.f, 0.f};
    float mrun = -1e30f, lrun = 0.f;

    for (int kt = 0; kt < 16; kt++) {
      const int k0 = kt * 32;
      bf16x8 kf0 = {0, 0, 0, 0, 0, 0, 0, 0};
      bf16x8 kf1 = {0, 0, 0, 0, 0, 0, 0, 0};
      if (quad < 2) {
        kf0 = *(const bf16x8*)&Ks[(k0 + fr) * 24 + quad * 8];
        kf1 = *(const bf16x8*)&Ks[(k0 + 16 + fr) * 24 + quad * 8];
      }
      f32x4 slo = __builtin_amdgcn_mfma_f32_16x16x32_bf16(kf0, qf, z4, 0, 0, 0);
      f32x4 shi = __builtin_amdgcn_mfma_f32_16x16x32_bf16(kf1, qf, z4, 0, 0, 0);
      float s[8];
#pragma unroll
      for (int r = 0; r < 4; r++) {
        s[r] = slo[r] * scale;
        s[4 + r] = shi[r] * scale;
      }
      float mx = s[0];
#pragma unroll
      for (int r = 1; r < 8; r++) mx = fmaxf(mx, s[r]);
      mx = fmaxf(mx, __shfl_xor(mx, 16));
      mx = fmaxf(mx, __shfl_xor(mx, 32));
      float nm = fmaxf(mrun, mx);
      float alpha = __expf(mrun - nm);
      mrun = nm;
      float p[8], rs = 0.f;
#pragma unroll
      for (int r = 0; r < 8; r++) {
        p[r] = __expf(s[r] - nm);
        rs += p[r];
      }
      rs += __shfl_xor(rs, 16);
      rs += __shfl_xor(rs, 32);
      lrun = lrun * alpha + rs;
#pragma unroll
      for (int r = 0; r < 4; r++) oacc[r] *= alpha;

      int pk0 = ((int)f2b(p[1]) << 16) | f2b(p[0]);
      int pk1 = ((int)f2b(p[3]) << 16) | f2b(p[2]);
      int pk2 = ((int)f2b(p[5]) << 16) | f2b(p[4]);
      int pk3 = ((int)f2b(p[7]) << 16) | f2b(p[6]);
      int B0a = __builtin_amdgcn_ds_bpermute(addrA, pk0);
      int B0b = __builtin_amdgcn_ds_bpermute(addrA, pk2);
      int B1a = __builtin_amdgcn_ds_bpermute(addrA, pk1);
      int B1b = __builtin_amdgcn_ds_bpermute(addrA, pk3);
      int B2a = __builtin_amdgcn_ds_bpermute(addrB, pk0);
      int B2b = __builtin_amdgcn_ds_bpermute(addrB, pk2);
      int B3a = __builtin_amdgcn_ds_bpermute(addrB, pk1);
      int B3b = __builtin_amdgcn_ds_bpermute(addrB, pk3);
      union { int i[4]; bf16x8 v; } pu;
      pu.i[0] = loTile ? B0a : B0b;
      pu.i[1] = loTile ? B1a : B1b;
      pu.i[2] = loTile ? B2a : B2b;
      pu.i[3] = loTile ? B3a : B3b;
      bf16x8 vf = *(const bf16x8*)&Vt[fr * 520 + k0 + quad * 8];
      oacc = __builtin_amdgcn_mfma_f32_16x16x32_bf16(vf, pu.v, oacc, 0, 0, 0);
    }

    float inv = __fdividef(1.f, lrun);
    ushort4 o;
    o.x = f2b(oacc[0] * inv);
    o.y = f2b(oacc[1] * inv);
    o.z = f2b(oacc[2] * inv);
    o.w = f2b(oacc[3] * inv);
    *(ushort4*)&Og[obase + (long)(q0 + fr) * DD + quad * 4] = o;
  }
}

// ---------------------------------------------------------------------------
__global__ __launch_bounds__(128) void pool_kernel(const u16* __restrict__ X,
                                                   float* __restrict__ P) {
  const int b = blockIdx.x, c = threadIdx.x;
  float acc = 0.f;
  for (int s = 0; s < SS; s++) acc += b2f(X[((long)b * SS + s) * DD + c]);
  P[b * DD + c] = acc * (1.f / 512.f);
}

__global__ __launch_bounds__(64) void cls_kernel(
    const float* __restrict__ P, const float* __restrict__ W1,
    const float* __restrict__ b1, const float* __restrict__ W2,
    const float* __restrict__ b2, float* __restrict__ L) {
  const int b = blockIdx.x, t = threadIdx.x;
  __shared__ float sp[128];
  __shared__ float sh[64];
  sp[t] = P[b * DD + t];
  sp[t + 64] = P[b * DD + 64 + t];
  __syncthreads();
  float acc = b1[t];
  for (int k = 0; k < 128; k++) acc += sp[k] * W1[k * 64 + t];
  sh[t] = fmaxf(acc, 0.f);
  __syncthreads();
  if (t < 5) {
    float acc2 = b2[t];
    for (int k = 0; k < 64; k++) acc2 += sh[k] * W2[k * 5 + t];
    L[b * 5 + t] = acc2;
  }
}

// ---------------------------------------------------------------------------
extern "C" void kernel_launch(void* const* d_in, const int* in_sizes, int n_in,
                              void* d_out, int out_size, void* d_ws, size_t ws_size,
                              hipStream_t stream) {
  const float* ts    = (const float*)d_in[0];
  const float* noise = (const float*)d_in[2];
  const float* dW1   = (const float*)d_in[3];
  const float* db1   = (const float*)d_in[4];
  const float* dW2   = (const float*)d_in[5];
  const float* db2   = (const float*)d_in[6];
  const float* dW3   = (const float*)d_in[7];
  const float* db3   = (const float*)d_in[8];
  const float* gW1   = (const float*)d_in[9];
  const float* gb1   = (const float*)d_in[10];
  const float* gW2   = (const float*)d_in[11];
  const float* gb2   = (const float*)d_in[12];
  const float* mind  = (const float*)d_in[13];
  const float* maxd  = (const float*)d_in[14];
  const float* in_W  = (const float*)d_in[15];
  const float* in_b  = (const float*)d_in[16];
  const float* Wq    = (const float*)d_in[17];
  const float* bq    = (const float*)d_in[18];
  const float* Wk    = (const float*)d_in[19];
  const float* bk    = (const float*)d_in[20];
  const float* Wv    = (const float*)d_in[21];
  const float* bv    = (const float*)d_in[22];
  const float* Wo    = (const float*)d_in[23];
  const float* bo    = (const float*)d_in[24];
  const float* ln1s  = (const float*)d_in[25];
  const float* ln1b  = (const float*)d_in[26];
  const float* fW1   = (const float*)d_in[27];
  const float* fb1   = (const float*)d_in[28];
  const float* fW2   = (const float*)d_in[29];
  const float* fb2   = (const float*)d_in[30];
  const float* ln2s  = (const float*)d_in[31];
  const float* ln2b  = (const float*)d_in[32];
  const float* cW1   = (const float*)d_in[33];
  const float* cb1   = (const float*)d_in[34];
  const float* cW2   = (const float*)d_in[35];
  const float* cb2   = (const float*)d_in[36];

  float* logits = (float*)d_out;
  float* sde    = logits + BB * 5;

  // Workspace (all-bf16 residual stream):
  char* W = (char*)d_ws;
  u16*  bxb    = (u16*)(W);                   //  8 MB bf16 x
  u16*  bh     = (u16*)(W + (8u << 20));      // 32 MB FFN hidden
  u16*  bob    = (u16*)(W + (40u << 20));     //  8 MB bf16 attn out
  u16*  bsb    = (u16*)(W + (48u << 20));     //  4 MB bf16 sde feats
  u16*  wts    = (u16*)(W + (52u << 20));     // ~1.5 MB bf16 weights
  float* bp    = (float*)(W + (54u << 20));   // pooled 64x128

  u16* inWt  = wts;                 // [128][64]
  u16* qkvWt = inWt + 8192;         // [4][3][128][128]
  u16* Wot   = qkvWt + 196608;      // [4][128][128]
  u16* fW1t  = Wot + 65536;         // [4][512][128]
  u16* fW2t  = fW1t + 262144;       // [4][128][512]

  prep_weights<<<dim3(64, 4, 7), 256, 0, stream>>>(in_W, Wq, Wk, Wv, Wo, fW1, fW2,
                                                   inWt, qkvWt, Wot, fW1t, fW2t);

  sde_kernel<<<64, 256, 0, stream>>>(ts, noise, dW1, db1, dW2, db2, dW3, db3,
                                     gW1, gb1, gW2, gb2, mind, maxd, sde, bsb);

  // x = sde @ in_W + in_b  (bf16)
  mfma_gemm<3><<<dim3(2, 256), 256, 0, stream>>>(bsb, inWt, in_b, bxb, 64, 128);

  for (int l = 0; l < 4; l++) {
    qkv_attn<<<BB * NHD, 256, 0, stream>>>(bxb, qkvWt + l * 49152,
                                           bq + l * DD, bk + l * DD, bv + l * DD,
                                           bob);
    gemm_ln<<<512, 256, 0, stream>>>(bob, Wot + l * 16384, bo + l * DD, bxb,
                                     ln1s + l * DD, ln1b + l * DD, bxb, 128);
    mfma_gemm<1><<<dim3(8, 256), 256, 0, stream>>>(bxb, fW1t + l * 65536,
                                                   fb1 + l * 512, bh, 128, 512);
    gemm_ln<<<512, 256, 0, stream>>>(bh, fW2t + l * 65536, fb2 + l * DD, bxb,
                                     ln2s + l * DD, ln2b + l * DD, bxb, 512);
  }

  pool_kernel<<<BB, 128, 0, stream>>>(bxb, bp);
  cls_kernel<<<BB, 64, 0, stream>>>(bp, cW1, cb1, cW2, cb2, logits);
}

// Round 3
// 1255.608 us; speedup vs baseline: 1.6362x; 1.0608x over previous
//
#include <hip/hip_runtime.h>
#include <hip/hip_bf16.h>
#include <math.h>

#define BB 64
#define SS 512
#define HH 64
#define DD 128
#define NHD 8
#define ROWS (BB*SS)   // 32768

typedef unsigned short u16;
typedef __attribute__((ext_vector_type(8))) short bf16x8;
typedef __attribute__((ext_vector_type(4))) float f32x4;

__device__ __forceinline__ u16 f2b(float f) {
  union { float f; unsigned u; } x; x.f = f;
  unsigned r = x.u + 0x7fffu + ((x.u >> 16) & 1u);
  return (u16)(r >> 16);
}

__device__ __forceinline__ float b2f(u16 u) {
  return __uint_as_float(((unsigned)u) << 16);
}

__device__ __forceinline__ float fast_tanh(float x) {
  float ax = fminf(fabsf(x), 15.f);
  float e = __expf(2.f * ax);
  float r = 1.f - __fdividef(2.f, e + 1.f);
  return copysignf(r, x);
}

__device__ __forceinline__ void barrier_lds() {
  __builtin_amdgcn_s_waitcnt(0xC07F);   // lgkmcnt(0) only
  __builtin_amdgcn_s_barrier();
}

// ---------------------------------------------------------------------------
// SDE scan v9: 512 threads (8 waves), ONE barrier per step.
// K-segmented stage B: wave w produces h1 segment [w*32,(w+1)*32) of its
// net (waves 0-3 drift, 4-7 diffusion) AND computes the 32-wide partial
// dot for all 64 B-outputs over that same segment -> A->B handoff is
// intra-wave (lgkmcnt only). Partials combine across waves at the single
// barrier (parity double-buffered). After it, every wave redundantly
// reduces (+bias, tanh/softplus), computes stage C (64 MACs/lane) and the
// y-update into a per-wave private y copy -> B->C and y->next-A handoffs
// are intra-wave. All LDS reads are broadcast / 2-way / consecutive.
// 133 weight floats/lane (< v8's 145, which fit without scratch).
// ---------------------------------------------------------------------------
__global__ __launch_bounds__(512, 2) void sde_kernel(
    const float* __restrict__ ts, const float* __restrict__ noise,
    const float* __restrict__ dW1, const float* __restrict__ db1,
    const float* __restrict__ dW2, const float* __restrict__ db2,
    const float* __restrict__ dW3, const float* __restrict__ db3,
    const float* __restrict__ gW1, const float* __restrict__ gb1,
    const float* __restrict__ gW2, const float* __restrict__ gb2,
    const float* __restrict__ pmind, const float* __restrict__ pmaxd,
    float* __restrict__ out, u16* __restrict__ outB) {
  const int b = blockIdx.x, t = threadIdx.x;
  const int w = t >> 6, lane = t & 63;
  const int drift = (w < 4) ? 1 : 0;
  const int wseg = w & 3;                 // K-segment index 0..3

  __shared__ float y_s[8][64];            // per-wave private y copy
  __shared__ float h1seg[8][32];          // per-wave A output segment
  __shared__ float h2c[8][64];            // per-wave private h2 copy
  __shared__ float pd[2][4][64];          // drift B partials (parity dbuf)
  __shared__ float pg[2][4][64];          // diffusion B partials
  __shared__ float tl_s[512], hs_s[512], sq_s[512];

  const float mind = fabsf(pmind[0]);
  const float maxd = fabsf(pmaxd[0]);

  // ---- stage A weights: out col = wseg*32 + (lane>>1), hA = K-half ----
  const int colA = wseg * 32 + (lane >> 1);
  const int hA = lane & 1;
  const float* W1 = drift ? dW1 : gW1;
  float wA[32];
#pragma unroll
  for (int k = 0; k < 32; k++) wA[k] = W1[(hA * 32 + k) * 128 + colA];
  const float wAt = W1[64 * 128 + colA];
  const float bA = (drift ? db1 : gb1)[colA];

  // ---- stage B partial weights: out col = lane, K rows wseg*32.. ----
  const float* W2 = drift ? dW2 : gW2;
  float wB[32];
#pragma unroll
  for (int k = 0; k < 32; k++) wB[k] = W2[(wseg * 32 + k) * 64 + lane];
  const float bBd = db2[lane], bBg = gb2[lane];

  // ---- stage C weights (every wave, redundant): out col = lane ----
  float wC[64];
#pragma unroll
  for (int k = 0; k < 64; k++) wC[k] = dW3[k * 64 + lane];
  const float bC = db3[lane];

  // ---- prologue ----
  tl_s[t & 511] = ts[(t & 511) * 3];
  __syncthreads();
  if (t < 511) {
    float hh = tl_s[t + 1] - tl_s[t];
    hs_s[t] = hh;
    sq_s[t] = sqrtf(hh);
  }

  float ymine = 0.1f;
  if (lane < 3) ymine = fminf(fmaxf(ts[b * 1536 + lane], 0.01f), 10.f);
  y_s[w][lane] = ymine;
  if (w == 0) out[(long)b * 32768 + lane] = ymine;
  if (w == 1) outB[((long)b * 512) * 64 + lane] = f2b(ymine);

  const long nofs = (long)b * 64 + lane;
  float nz0 = noise[nofs];
  float nz1 = noise[4096 + nofs];
  float nz2 = noise[2 * 4096 + nofs];
  float nz3 = noise[3 * 4096 + nofs];
  __syncthreads();

  for (int i = 0; i < 511; i++) {
    const int buf = i & 1;
    const float tl = tl_s[i];
    const float hh = hs_s[i];
    const float sq = sq_s[i];

    // noise shift-register (compile-time slots)
    const float nz = nz0;
    nz0 = nz1; nz1 = nz2; nz2 = nz3;
    if (i + 4 < 511) nz3 = noise[(long)(i + 4) * 4096 + nofs];

    // ---- stage A: 2 lanes/out, 32 MACs, own y copy (broadcast reads) ----
    float a0 = 0.f, a1 = 0.f, a2 = 0.f, a3 = 0.f;
#pragma unroll
    for (int g = 0; g < 8; g++) {
      float4 yv = *(const float4*)&y_s[w][hA * 32 + g * 4];
      a0 += yv.x * wA[g * 4 + 0];
      a1 += yv.y * wA[g * 4 + 1];
      a2 += yv.z * wA[g * 4 + 2];
      a3 += yv.w * wA[g * 4 + 3];
    }
    float p1 = (a0 + a1) + (a2 + a3);
    p1 += hA ? (tl * wAt) : bA;
    p1 += __shfl_xor(p1, 1);
    float h1v = fast_tanh(p1);
    if (hA == 0) h1seg[w][lane >> 1] = h1v;
    // intra-wave handoff: no barrier

    // ---- stage B partial: 32 MACs over own segment (broadcast reads) ----
    float c0 = 0.f, c1 = 0.f, c2 = 0.f, c3 = 0.f;
#pragma unroll
    for (int g = 0; g < 8; g++) {
      float4 hv = *(const float4*)&h1seg[w][g * 4];
      c0 += hv.x * wB[g * 4 + 0];
      c1 += hv.y * wB[g * 4 + 1];
      c2 += hv.z * wB[g * 4 + 2];
      c3 += hv.w * wB[g * 4 + 3];
    }
    float psum = (c0 + c1) + (c2 + c3);
    if (drift) pd[buf][wseg][lane] = psum;
    else       pg[buf][wseg][lane] = psum;

    barrier_lds();                        // the ONE barrier per step

    // ---- reduce (redundant per wave): h2[lane], gc[lane] ----
    float sd = ((pd[buf][0][lane] + pd[buf][1][lane]) +
                (pd[buf][2][lane] + pd[buf][3][lane])) + bBd;
    float h2v = fast_tanh(sd);
    float sg = ((pg[buf][0][lane] + pg[buf][1][lane]) +
                (pg[buf][2][lane] + pg[buf][3][lane])) + bBg;
    float gc = fmaxf(sg, 0.f) + __logf(1.f + __expf(-fabsf(sg))) + mind;
    h2c[w][lane] = h2v;
    // intra-wave handoff: no barrier

    // ---- stage C (redundant per wave): 64 MACs, broadcast reads ----
    float d0 = 0.f, d1 = 0.f, d2 = 0.f, d3 = 0.f;
#pragma unroll
    for (int g = 0; g < 16; g++) {
      float4 hv = *(const float4*)&h2c[w][g * 4];
      d0 += hv.x * wC[g * 4 + 0];
      d1 += hv.y * wC[g * 4 + 1];
      d2 += hv.z * wC[g * 4 + 2];
      d3 += hv.w * wC[g * 4 + 3];
    }
    float dc = fminf(fmaxf((d0 + d1) + (d2 + d3) + bC, -maxd), maxd);

    // ---- y update (redundant per wave, own copy) ----
    float yo = ymine;
    float yn = yo + dc * yo * hh + gc * fminf(fmaxf(yo, -10.f), 10.f) * nz * sq;
    yn = fminf(fmaxf(yn, 0.01f), 10.f);
    y_s[w][lane] = yn;
    ymine = yn;
    if (w == 0) out[(long)b * 32768 + (i + 1) * 64 + lane] = yn;
    if (w == 1) outB[((long)b * 512 + i + 1) * 64 + lane] = f2b(yn);
  }
}

// ---------------------------------------------------------------------------
__global__ __launch_bounds__(256) void prep_weights(
    const float* __restrict__ in_W, const float* __restrict__ Wq,
    const float* __restrict__ Wk, const float* __restrict__ Wv,
    const float* __restrict__ Wo, const float* __restrict__ fW1,
    const float* __restrict__ fW2,
    u16* __restrict__ inWt, u16* __restrict__ qkvWt, u16* __restrict__ Wot,
    u16* __restrict__ fW1t, u16* __restrict__ fW2t) {
  const int z = blockIdx.z, layer = blockIdx.y, tile = blockIdx.x;
  const float* src; u16* dst; int R, C, nl;
  switch (z) {
    case 0: src = in_W; dst = inWt; R = 64; C = 128; nl = 1; break;
    case 1: src = Wq + layer * 16384; dst = qkvWt + layer * 49152; R = 128; C = 128; nl = 4; break;
    case 2: src = Wk + layer * 16384; dst = qkvWt + layer * 49152 + 16384; R = 128; C = 128; nl = 4; break;
    case 3: src = Wv + layer * 16384; dst = qkvWt + layer * 49152 + 32768; R = 128; C = 128; nl = 4; break;
    case 4: src = Wo + layer * 16384; dst = Wot + layer * 16384; R = 128; C = 128; nl = 4; break;
    case 5: src = fW1 + layer * 65536; dst = fW1t + layer * 65536; R = 128; C = 512; nl = 4; break;
    default: src = fW2 + layer * 65536; dst = fW2t + layer * 65536; R = 512; C = 128; nl = 4; break;
  }
  const int nt = (R / 32) * (C / 32);
  if (layer >= nl || tile >= nt) return;
  const int tpr = C / 32;
  const int r0 = (tile / tpr) * 32, c0 = (tile % tpr) * 32;
  __shared__ float tl[32][33];
  const int tx = threadIdx.x & 31, ty = threadIdx.x >> 5;
#pragma unroll
  for (int p = 0; p < 4; p++)
    tl[ty + 8 * p][tx] = src[(long)(r0 + ty + 8 * p) * C + c0 + tx];
  __syncthreads();
#pragma unroll
  for (int p = 0; p < 4; p++)
    dst[(long)(c0 + ty + 8 * p) * R + r0 + tx] = f2b(tl[tx][ty + 8 * p]);
}

// ---------------------------------------------------------------------------
// bf16 MFMA GEMM. MODE 1: bf16+relu. MODE 3: bf16.
// ---------------------------------------------------------------------------
template <int MODE>
__global__ __launch_bounds__(256) void mfma_gemm(
    const u16* __restrict__ A, const u16* __restrict__ Bt,
    const float* __restrict__ bias, u16* __restrict__ outB, int K, int N) {
  __shared__ u16 As[128 * 40];
  __shared__ u16 Bs[64 * 40];
  const int t = threadIdx.x;
  const int nb = blockIdx.x * 64;
  const long mb = (long)blockIdx.y * 128;
  const int lane = t & 63, wave = t >> 6;
  const int wm = (wave >> 1) * 64, wn = (wave & 1) * 32;
  const int fr = lane & 15, quad = lane >> 4;

  f32x4 zero = {0.f, 0.f, 0.f, 0.f};
  f32x4 acc[4][2];
#pragma unroll
  for (int mi = 0; mi < 4; mi++)
#pragma unroll
    for (int ni = 0; ni < 2; ni++) acc[mi][ni] = zero;

  for (int k0 = 0; k0 < K; k0 += 32) {
#pragma unroll
    for (int p = 0; p < 2; p++) {
      int idx = t + p * 256, row = idx >> 2, seg = idx & 3;
      int4 v = *(const int4*)&A[(mb + row) * K + k0 + seg * 8];
      *(int4*)&As[row * 40 + seg * 8] = v;
    }
    {
      int row = t >> 2, seg = t & 3;
      int4 v = *(const int4*)&Bt[(long)(nb + row) * K + k0 + seg * 8];
      *(int4*)&Bs[row * 40 + seg * 8] = v;
    }
    __syncthreads();
    bf16x8 af[4], bfr[2];
#pragma unroll
    for (int mi = 0; mi < 4; mi++)
      af[mi] = *(const bf16x8*)&As[(wm + mi * 16 + fr) * 40 + quad * 8];
#pragma unroll
    for (int ni = 0; ni < 2; ni++)
      bfr[ni] = *(const bf16x8*)&Bs[(wn + ni * 16 + fr) * 40 + quad * 8];
#pragma unroll
    for (int mi = 0; mi < 4; mi++)
#pragma unroll
      for (int ni = 0; ni < 2; ni++)
        acc[mi][ni] = __builtin_amdgcn_mfma_f32_16x16x32_bf16(
            af[mi], bfr[ni], acc[mi][ni], 0, 0, 0);
    __syncthreads();
  }

#pragma unroll
  for (int mi = 0; mi < 4; mi++)
#pragma unroll
    for (int ni = 0; ni < 2; ni++) {
      int col = nb + wn + ni * 16 + fr;
      float bv = bias[col];
#pragma unroll
      for (int r = 0; r < 4; r++) {
        long row = mb + wm + mi * 16 + quad * 4 + r;
        float v = acc[mi][ni][r] + bv;
        if (MODE == 1) {
          outB[row * N + col] = f2b(fmaxf(v, 0.f));
        } else {
          outB[row * N + col] = f2b(v);
        }
      }
    }
}

// ---------------------------------------------------------------------------
// Fused GEMM + residual(bf16) + LayerNorm -> bf16. Tile 64x128, 512 blocks.
// ---------------------------------------------------------------------------
__global__ __launch_bounds__(256) void gemm_ln(
    const u16* __restrict__ A, const u16* __restrict__ Bt,
    const float* __restrict__ bias, const u16* __restrict__ resid,
    const float* __restrict__ gamma, const float* __restrict__ beta,
    u16* __restrict__ outB, int K) {
  __shared__ u16 As[64 * 40];
  __shared__ u16 Bs[128 * 40];
  __shared__ float s1[2][64], s2[2][64];
  const int t = threadIdx.x;
  const long mb = (long)blockIdx.x * 64;
  const int lane = t & 63, wave = t >> 6;
  const int wm = (wave >> 1) * 32, wn = (wave & 1) * 64;
  const int fr = lane & 15, quad = lane >> 4;

  f32x4 zero = {0.f, 0.f, 0.f, 0.f};
  f32x4 acc[2][4];
#pragma unroll
  for (int mi = 0; mi < 2; mi++)
#pragma unroll
    for (int ni = 0; ni < 4; ni++) acc[mi][ni] = zero;

  for (int k0 = 0; k0 < K; k0 += 32) {
    {
      int row = t >> 2, seg = t & 3;
      *(int4*)&As[row * 40 + seg * 8] =
          *(const int4*)&A[(mb + row) * K + k0 + seg * 8];
    }
#pragma unroll
    for (int p = 0; p < 2; p++) {
      int idx = t + p * 256, row = idx >> 2, seg = idx & 3;
      *(int4*)&Bs[row * 40 + seg * 8] =
          *(const int4*)&Bt[(long)row * K + k0 + seg * 8];
    }
    __syncthreads();
    bf16x8 af[2], bfr[4];
#pragma unroll
    for (int mi = 0; mi < 2; mi++)
      af[mi] = *(const bf16x8*)&As[(wm + mi * 16 + fr) * 40 + quad * 8];
#pragma unroll
    for (int ni = 0; ni < 4; ni++)
      bfr[ni] = *(const bf16x8*)&Bs[(wn + ni * 16 + fr) * 40 + quad * 8];
#pragma unroll
    for (int mi = 0; mi < 2; mi++)
#pragma unroll
      for (int ni = 0; ni < 4; ni++)
        acc[mi][ni] = __builtin_amdgcn_mfma_f32_16x16x32_bf16(
            af[mi], bfr[ni], acc[mi][ni], 0, 0, 0);
    __syncthreads();
  }

  float bv[4], gv[4], be[4];
#pragma unroll
  for (int ni = 0; ni < 4; ni++) {
    int col = wn + ni * 16 + fr;
    bv[ni] = bias[col];
    gv[ni] = gamma[col];
    be[ni] = beta[col];
  }

#pragma unroll
  for (int mi = 0; mi < 2; mi++) {
#pragma unroll
    for (int r = 0; r < 4; r++) {
      int rloc = wm + mi * 16 + quad * 4 + r;
      long row = mb + rloc;
      float s = 0.f, ss = 0.f;
#pragma unroll
      for (int ni = 0; ni < 4; ni++) {
        int col = wn + ni * 16 + fr;
        float v = acc[mi][ni][r] + bv[ni] + b2f(resid[row * DD + col]);
        acc[mi][ni][r] = v;
        s += v;
        ss += v * v;
      }
      s += __shfl_xor(s, 1); ss += __shfl_xor(ss, 1);
      s += __shfl_xor(s, 2); ss += __shfl_xor(ss, 2);
      s += __shfl_xor(s, 4); ss += __shfl_xor(ss, 4);
      s += __shfl_xor(s, 8); ss += __shfl_xor(ss, 8);
      if (fr == 0) {
        s1[wn >> 6][rloc] = s;
        s2[wn >> 6][rloc] = ss;
      }
    }
  }
  __syncthreads();

#pragma unroll
  for (int mi = 0; mi < 2; mi++) {
#pragma unroll
    for (int r = 0; r < 4; r++) {
      int rloc = wm + mi * 16 + quad * 4 + r;
      long row = mb + rloc;
      float sum = s1[0][rloc] + s1[1][rloc];
      float sumsq = s2[0][rloc] + s2[1][rloc];
      float mean = sum * (1.f / 128.f);
      float var = sumsq * (1.f / 128.f) - mean * mean;
      float rstd = rsqrtf(var + 1e-5f);
#pragma unroll
      for (int ni = 0; ni < 4; ni++) {
        int col = wn + ni * 16 + fr;
        float o = (acc[mi][ni][r] - mean) * rstd * gv[ni] + be[ni];
        outB[row * DD + col] = f2b(o);
      }
    }
  }
}

// ---------------------------------------------------------------------------
// Fused QKV-projection + flash attention. One block per (b,h), 512 blocks,
// 2 blocks/CU (64.3 KB LDS). Block computes its head's Q/K/V (512x16 each,
// K=128 — head slices exactly partition the QKV GEMM) into LDS, then runs
// the S^T-orientation online-softmax loop (verified round 8).
// ---------------------------------------------------------------------------
__global__ __launch_bounds__(256, 2) void qkv_attn(
    const u16* __restrict__ xb, const u16* __restrict__ qkvW,
    const float* __restrict__ bq, const float* __restrict__ bk,
    const float* __restrict__ bv, u16* __restrict__ Og) {
  const int bh = blockIdx.x;
  const int b = bh >> 3, h = bh & 7;
  __shared__ u16 Ks[512 * 24];     // [key][d]  (24 KB)
  __shared__ u16 Vt[16 * 520];     // [d][key]  (16.3 KB)
  __shared__ u16 Qs[512 * 24];     // [q][d]    (24 KB)
  const int t = threadIdx.x;
  const int w = t >> 6, lane = t & 63;
  const int fr = lane & 15, quad = lane >> 4;
  const long obase = ((long)b * SS) * DD + h * 16;
  const u16* xrow = xb + (long)b * SS * DD;

  // ---- head weight B-frags (register-resident) ----
  const u16* Wq_h = qkvW + (h * 16) * 128;
  const u16* Wk_h = qkvW + 16384 + (h * 16) * 128;
  const u16* Wv_h = qkvW + 32768 + (h * 16) * 128;
  bf16x8 wqf[4], wkf[4], wvf[4];
#pragma unroll
  for (int c = 0; c < 4; c++) {
    wqf[c] = *(const bf16x8*)&Wq_h[fr * 128 + c * 32 + quad * 8];
    wkf[c] = *(const bf16x8*)&Wk_h[fr * 128 + c * 32 + quad * 8];
    wvf[c] = *(const bf16x8*)&Wv_h[fr * 128 + c * 32 + quad * 8];
  }
  const float bqv = bq[h * 16 + fr];
  const float bkv = bk[h * 16 + fr];
  const float bvv = bv[h * 16 + fr];
  const f32x4 z4 = {0.f, 0.f, 0.f, 0.f};

  // ---- project Q/K/V for this head into LDS ----
  for (int tile = w; tile < 32; tile += 4) {
    const int t0 = tile * 16;
    bf16x8 af[4];
#pragma unroll
    for (int c = 0; c < 4; c++)
      af[c] = *(const bf16x8*)&xrow[(t0 + fr) * 128 + c * 32 + quad * 8];
    f32x4 qa = z4, ka = z4, va = z4;
#pragma unroll
    for (int c = 0; c < 4; c++) {
      qa = __builtin_amdgcn_mfma_f32_16x16x32_bf16(af[c], wqf[c], qa, 0, 0, 0);
      ka = __builtin_amdgcn_mfma_f32_16x16x32_bf16(af[c], wkf[c], ka, 0, 0, 0);
      va = __builtin_amdgcn_mfma_f32_16x16x32_bf16(af[c], wvf[c], va, 0, 0, 0);
    }
    // C-layout: lane holds (d = fr, row = t0 + quad*4 + r)
#pragma unroll
    for (int r = 0; r < 4; r++) {
      int row = t0 + quad * 4 + r;
      Qs[row * 24 + fr] = f2b(qa[r] + bqv);
      Ks[row * 24 + fr] = f2b(ka[r] + bkv);
      Vt[fr * 520 + row] = f2b(va[r] + bvv);
    }
  }
  __syncthreads();

  // ---- flash attention (S^T orientation) ----
  const float scale = 0.25f;                 // 1/sqrt(16)
  const int addrA = (((quad & 1) * 32) + fr) * 4;
  const int addrB = addrA + 64;
  const bool loTile = (quad < 2);

  for (int qt = w; qt < 32; qt += 4) {
    const int q0 = qt * 16;
    bf16x8 qf = {0, 0, 0, 0, 0, 0, 0, 0};
    if (quad < 2)
      qf = *(const bf16x8*)&Qs[(q0 + fr) * 24 + quad * 8];
    f32x4 oacc = {0.f, 0.f, 0.f, 0.f};
    float mrun = -1e30f, lrun = 0.f;

    for (int kt = 0; kt < 16; kt++) {
      const int k0 = kt * 32;
      bf16x8 kf0 = {0, 0, 0, 0, 0, 0, 0, 0};
      bf16x8 kf1 = {0, 0, 0, 0, 0, 0, 0, 0};
      if (quad < 2) {
        kf0 = *(const bf16x8*)&Ks[(k0 + fr) * 24 + quad * 8];
        kf1 = *(const bf16x8*)&Ks[(k0 + 16 + fr) * 24 + quad * 8];
      }
      f32x4 slo = __builtin_amdgcn_mfma_f32_16x16x32_bf16(kf0, qf, z4, 0, 0, 0);
      f32x4 shi = __builtin_amdgcn_mfma_f32_16x16x32_bf16(kf1, qf, z4, 0, 0, 0);
      float s[8];
#pragma unroll
      for (int r = 0; r < 4; r++) {
        s[r] = slo[r] * scale;
        s[4 + r] = shi[r] * scale;
      }
      float mx = s[0];
#pragma unroll
      for (int r = 1; r < 8; r++) mx = fmaxf(mx, s[r]);
      mx = fmaxf(mx, __shfl_xor(mx, 16));
      mx = fmaxf(mx, __shfl_xor(mx, 32));
      float nm = fmaxf(mrun, mx);
      float alpha = __expf(mrun - nm);
      mrun = nm;
      float p[8], rs = 0.f;
#pragma unroll
      for (int r = 0; r < 8; r++) {
        p[r] = __expf(s[r] - nm);
        rs += p[r];
      }
      rs += __shfl_xor(rs, 16);
      rs += __shfl_xor(rs, 32);
      lrun = lrun * alpha + rs;
#pragma unroll
      for (int r = 0; r < 4; r++) oacc[r] *= alpha;

      int pk0 = ((int)f2b(p[1]) << 16) | f2b(p[0]);
      int pk1 = ((int)f2b(p[3]) << 16) | f2b(p[2]);
      int pk2 = ((int)f2b(p[5]) << 16) | f2b(p[4]);
      int pk3 = ((int)f2b(p[7]) << 16) | f2b(p[6]);
      int B0a = __builtin_amdgcn_ds_bpermute(addrA, pk0);
      int B0b = __builtin_amdgcn_ds_bpermute(addrA, pk2);
      int B1a = __builtin_amdgcn_ds_bpermute(addrA, pk1);
      int B1b = __builtin_amdgcn_ds_bpermute(addrA, pk3);
      int B2a = __builtin_amdgcn_ds_bpermute(addrB, pk0);
      int B2b = __builtin_amdgcn_ds_bpermute(addrB, pk2);
      int B3a = __builtin_amdgcn_ds_bpermute(addrB, pk1);
      int B3b = __builtin_amdgcn_ds_bpermute(addrB, pk3);
      union { int i[4]; bf16x8 v; } pu;
      pu.i[0] = loTile ? B0a : B0b;
      pu.i[1] = loTile ? B1a : B1b;
      pu.i[2] = loTile ? B2a : B2b;
      pu.i[3] = loTile ? B3a : B3b;
      bf16x8 vf = *(const bf16x8*)&Vt[fr * 520 + k0 + quad * 8];
      oacc = __builtin_amdgcn_mfma_f32_16x16x32_bf16(vf, pu.v, oacc, 0, 0, 0);
    }

    float inv = __fdividef(1.f, lrun);
    ushort4 o;
    o.x = f2b(oacc[0] * inv);
    o.y = f2b(oacc[1] * inv);
    o.z = f2b(oacc[2] * inv);
    o.w = f2b(oacc[3] * inv);
    *(ushort4*)&Og[obase + (long)(q0 + fr) * DD + quad * 4] = o;
  }
}

// ---------------------------------------------------------------------------
__global__ __launch_bounds__(128) void pool_kernel(const u16* __restrict__ X,
                                                   float* __restrict__ P) {
  const int b = blockIdx.x, c = threadIdx.x;
  float acc = 0.f;
  for (int s = 0; s < SS; s++) acc += b2f(X[((long)b * SS + s) * DD + c]);
  P[b * DD + c] = acc * (1.f / 512.f);
}

__global__ __launch_bounds__(64) void cls_kernel(
    const float* __restrict__ P, const float* __restrict__ W1,
    const float* __restrict__ b1, const float* __restrict__ W2,
    const float* __restrict__ b2, float* __restrict__ L) {
  const int b = blockIdx.x, t = threadIdx.x;
  __shared__ float sp[128];
  __shared__ float sh[64];
  sp[t] = P[b * DD + t];
  sp[t + 64] = P[b * DD + 64 + t];
  __syncthreads();
  float acc = b1[t];
  for (int k = 0; k < 128; k++) acc += sp[k] * W1[k * 64 + t];
  sh[t] = fmaxf(acc, 0.f);
  __syncthreads();
  if (t < 5) {
    float acc2 = b2[t];
    for (int k = 0; k < 64; k++) acc2 += sh[k] * W2[k * 5 + t];
    L[b * 5 + t] = acc2;
  }
}

// ---------------------------------------------------------------------------
extern "C" void kernel_launch(void* const* d_in, const int* in_sizes, int n_in,
                              void* d_out, int out_size, void* d_ws, size_t ws_size,
                              hipStream_t stream) {
  const float* ts    = (const float*)d_in[0];
  const float* noise = (const float*)d_in[2];
  const float* dW1   = (const float*)d_in[3];
  const float* db1   = (const float*)d_in[4];
  const float* dW2   = (const float*)d_in[5];
  const float* db2   = (const float*)d_in[6];
  const float* dW3   = (const float*)d_in[7];
  const float* db3   = (const float*)d_in[8];
  const float* gW1   = (const float*)d_in[9];
  const float* gb1   = (const float*)d_in[10];
  const float* gW2   = (const float*)d_in[11];
  const float* gb2   = (const float*)d_in[12];
  const float* mind  = (const float*)d_in[13];
  const float* maxd  = (const float*)d_in[14];
  const float* in_W  = (const float*)d_in[15];
  const float* in_b  = (const float*)d_in[16];
  const float* Wq    = (const float*)d_in[17];
  const float* bq    = (const float*)d_in[18];
  const float* Wk    = (const float*)d_in[19];
  const float* bk    = (const float*)d_in[20];
  const float* Wv    = (const float*)d_in[21];
  const float* bv    = (const float*)d_in[22];
  const float* Wo    = (const float*)d_in[23];
  const float* bo    = (const float*)d_in[24];
  const float* ln1s  = (const float*)d_in[25];
  const float* ln1b  = (const float*)d_in[26];
  const float* fW1   = (const float*)d_in[27];
  const float* fb1   = (const float*)d_in[28];
  const float* fW2   = (const float*)d_in[29];
  const float* fb2   = (const float*)d_in[30];
  const float* ln2s  = (const float*)d_in[31];
  const float* ln2b  = (const float*)d_in[32];
  const float* cW1   = (const float*)d_in[33];
  const float* cb1   = (const float*)d_in[34];
  const float* cW2   = (const float*)d_in[35];
  const float* cb2   = (const float*)d_in[36];

  float* logits = (float*)d_out;
  float* sde    = logits + BB * 5;

  // Workspace (all-bf16 residual stream):
  char* W = (char*)d_ws;
  u16*  bxb    = (u16*)(W);                   //  8 MB bf16 x
  u16*  bh     = (u16*)(W + (8u << 20));      // 32 MB FFN hidden
  u16*  bob    = (u16*)(W + (40u << 20));     //  8 MB bf16 attn out
  u16*  bsb    = (u16*)(W + (48u << 20));     //  4 MB bf16 sde feats
  u16*  wts    = (u16*)(W + (52u << 20));     // ~1.5 MB bf16 weights
  float* bp    = (float*)(W + (54u << 20));   // pooled 64x128

  u16* inWt  = wts;                 // [128][64]
  u16* qkvWt = inWt + 8192;         // [4][3][128][128]
  u16* Wot   = qkvWt + 196608;      // [4][128][128]
  u16* fW1t  = Wot + 65536;         // [4][512][128]
  u16* fW2t  = fW1t + 262144;       // [4][128][512]

  prep_weights<<<dim3(64, 4, 7), 256, 0, stream>>>(in_W, Wq, Wk, Wv, Wo, fW1, fW2,
                                                   inWt, qkvWt, Wot, fW1t, fW2t);

  sde_kernel<<<64, 512, 0, stream>>>(ts, noise, dW1, db1, dW2, db2, dW3, db3,
                                     gW1, gb1, gW2, gb2, mind, maxd, sde, bsb);

  // x = sde @ in_W + in_b  (bf16)
  mfma_gemm<3><<<dim3(2, 256), 256, 0, stream>>>(bsb, inWt, in_b, bxb, 64, 128);

  for (int l = 0; l < 4; l++) {
    qkv_attn<<<BB * NHD, 256, 0, stream>>>(bxb, qkvWt + l * 49152,
                                           bq + l * DD, bk + l * DD, bv + l * DD,
                                           bob);
    gemm_ln<<<512, 256, 0, stream>>>(bob, Wot + l * 16384, bo + l * DD, bxb,
                                     ln1s + l * DD, ln1b + l * DD, bxb, 128);
    mfma_gemm<1><<<dim3(8, 256), 256, 0, stream>>>(bxb, fW1t + l * 65536,
                                                   fb1 + l * 512, bh, 128, 512);
    gemm_ln<<<512, 256, 0, stream>>>(bh, fW2t + l * 65536, fb2 + l * DD, bxb,
                                     ln2s + l * DD, ln2b + l * DD, bxb, 512);
  }

  pool_kernel<<<BB, 128, 0, stream>>>(bxb, bp);
  cls_kernel<<<BB, 64, 0, stream>>>(bp, cW1, cb1, cW2, cb2, logits);
}

// Round 4
// 1252.253 us; speedup vs baseline: 1.6406x; 1.0027x over previous
//
#include <hip/hip_runtime.h>
#include <hip/hip_bf16.h>
#include <math.h>

#define BB 64
#define SS 512
#define HH 64
#define DD 128
#define NHD 8
#define ROWS (BB*SS)   // 32768

typedef unsigned short u16;
typedef __attribute__((ext_vector_type(8))) short bf16x8;
typedef __attribute__((ext_vector_type(4))) float f32x4;

__device__ __forceinline__ u16 f2b(float f) {
  union { float f; unsigned u; } x; x.f = f;
  unsigned r = x.u + 0x7fffu + ((x.u >> 16) & 1u);
  return (u16)(r >> 16);
}

__device__ __forceinline__ float b2f(u16 u) {
  return __uint_as_float(((unsigned)u) << 16);
}

__device__ __forceinline__ float fast_tanh(float x) {
  float ax = fminf(fabsf(x), 15.f);
  float e = __expf(2.f * ax);
  float r = 1.f - __fdividef(2.f, e + 1.f);
  return copysignf(r, x);
}

__device__ __forceinline__ void barrier_lds() {
  __builtin_amdgcn_s_waitcnt(0xC07F);   // lgkmcnt(0) only
  __builtin_amdgcn_s_barrier();
}

// pair-combine via DPP (VALU, not LDS pipe): add value of lane^1
__device__ __forceinline__ float dpp_xor1_add(float x) {
  int pi = __float_as_int(x);
  int po = __builtin_amdgcn_update_dpp(0, pi, 0xB1 /*quad_perm [1,0,3,2]*/,
                                       0xF, 0xF, true);
  return x + __int_as_float(po);
}

// ---------------------------------------------------------------------------
// SDE scan v10: v9's 1-barrier structure (8 waves: 0-3 drift, 4-7 diffusion,
// K-segmented stage B, redundant reduce/C per wave, per-wave private y).
// Changes vs v9:
//  - amdgpu_waves_per_eu(2,2): pin occupancy at exactly 2 waves/EU (the real
//    value: 64 blocks / 64 CUs, 8 waves each) so the allocator keeps the
//    ~130 weight floats in ARCH VGPRs instead of AGPR-parking them
//    (v9: VGPR_Count=92 + accvgpr moves = ~500 issue-cyc/SIMD/step).
//  - stage-A pair combine via v_mov_dpp quad_perm (VALU) instead of
//    __shfl_xor -> ds_bpermute (LDS pipe) on the serial chain.
// ---------------------------------------------------------------------------
__global__ __attribute__((amdgpu_flat_work_group_size(512, 512)))
__attribute__((amdgpu_waves_per_eu(2, 2))) void sde_kernel(
    const float* __restrict__ ts, const float* __restrict__ noise,
    const float* __restrict__ dW1, const float* __restrict__ db1,
    const float* __restrict__ dW2, const float* __restrict__ db2,
    const float* __restrict__ dW3, const float* __restrict__ db3,
    const float* __restrict__ gW1, const float* __restrict__ gb1,
    const float* __restrict__ gW2, const float* __restrict__ gb2,
    const float* __restrict__ pmind, const float* __restrict__ pmaxd,
    float* __restrict__ out, u16* __restrict__ outB) {
  const int b = blockIdx.x, t = threadIdx.x;
  const int w = t >> 6, lane = t & 63;
  const int drift = (w < 4) ? 1 : 0;
  const int wseg = w & 3;                 // K-segment index 0..3

  __shared__ float y_s[8][64];            // per-wave private y copy
  __shared__ float h1seg[8][32];          // per-wave A output segment
  __shared__ float h2c[8][64];            // per-wave private h2 copy
  __shared__ float pd[2][4][64];          // drift B partials (parity dbuf)
  __shared__ float pg[2][4][64];          // diffusion B partials
  __shared__ float tl_s[512], hs_s[512], sq_s[512];

  const float mind = fabsf(pmind[0]);
  const float maxd = fabsf(pmaxd[0]);

  // ---- stage A weights: out col = wseg*32 + (lane>>1), hA = K-half ----
  const int colA = wseg * 32 + (lane >> 1);
  const int hA = lane & 1;
  const float* W1 = drift ? dW1 : gW1;
  float wA[32];
#pragma unroll
  for (int k = 0; k < 32; k++) wA[k] = W1[(hA * 32 + k) * 128 + colA];
  const float wAt = W1[64 * 128 + colA];
  const float bA = (drift ? db1 : gb1)[colA];

  // ---- stage B partial weights: out col = lane, K rows wseg*32.. ----
  const float* W2 = drift ? dW2 : gW2;
  float wB[32];
#pragma unroll
  for (int k = 0; k < 32; k++) wB[k] = W2[(wseg * 32 + k) * 64 + lane];
  const float bBd = db2[lane], bBg = gb2[lane];

  // ---- stage C weights (every wave, redundant): out col = lane ----
  float wC[64];
#pragma unroll
  for (int k = 0; k < 64; k++) wC[k] = dW3[k * 64 + lane];
  const float bC = db3[lane];

  // ---- prologue ----
  tl_s[t & 511] = ts[(t & 511) * 3];
  __syncthreads();
  if (t < 511) {
    float hh = tl_s[t + 1] - tl_s[t];
    hs_s[t] = hh;
    sq_s[t] = sqrtf(hh);
  }

  float ymine = 0.1f;
  if (lane < 3) ymine = fminf(fmaxf(ts[b * 1536 + lane], 0.01f), 10.f);
  y_s[w][lane] = ymine;
  if (w == 0) out[(long)b * 32768 + lane] = ymine;
  if (w == 1) outB[((long)b * 512) * 64 + lane] = f2b(ymine);

  const long nofs = (long)b * 64 + lane;
  float nz0 = noise[nofs];
  float nz1 = noise[4096 + nofs];
  float nz2 = noise[2 * 4096 + nofs];
  float nz3 = noise[3 * 4096 + nofs];
  __syncthreads();

  for (int i = 0; i < 511; i++) {
    const int buf = i & 1;
    const float tl = tl_s[i];
    const float hh = hs_s[i];
    const float sq = sq_s[i];

    // noise shift-register (compile-time slots)
    const float nz = nz0;
    nz0 = nz1; nz1 = nz2; nz2 = nz3;
    if (i + 4 < 511) nz3 = noise[(long)(i + 4) * 4096 + nofs];

    // ---- stage A: 2 lanes/out, 32 MACs, own y copy (broadcast reads) ----
    float a0 = 0.f, a1 = 0.f, a2 = 0.f, a3 = 0.f;
#pragma unroll
    for (int g = 0; g < 8; g++) {
      float4 yv = *(const float4*)&y_s[w][hA * 32 + g * 4];
      a0 += yv.x * wA[g * 4 + 0];
      a1 += yv.y * wA[g * 4 + 1];
      a2 += yv.z * wA[g * 4 + 2];
      a3 += yv.w * wA[g * 4 + 3];
    }
    float p1 = (a0 + a1) + (a2 + a3);
    p1 += hA ? (tl * wAt) : bA;
    p1 = dpp_xor1_add(p1);                // VALU pair-combine (no LDS pipe)
    float h1v = fast_tanh(p1);
    if (hA == 0) h1seg[w][lane >> 1] = h1v;
    // intra-wave handoff: no barrier

    // ---- stage B partial: 32 MACs over own segment (broadcast reads) ----
    float c0 = 0.f, c1 = 0.f, c2 = 0.f, c3 = 0.f;
#pragma unroll
    for (int g = 0; g < 8; g++) {
      float4 hv = *(const float4*)&h1seg[w][g * 4];
      c0 += hv.x * wB[g * 4 + 0];
      c1 += hv.y * wB[g * 4 + 1];
      c2 += hv.z * wB[g * 4 + 2];
      c3 += hv.w * wB[g * 4 + 3];
    }
    float psum = (c0 + c1) + (c2 + c3);
    if (drift) pd[buf][wseg][lane] = psum;
    else       pg[buf][wseg][lane] = psum;

    barrier_lds();                        // the ONE barrier per step

    // ---- reduce (redundant per wave): h2[lane], gc[lane] ----
    float sd = ((pd[buf][0][lane] + pd[buf][1][lane]) +
                (pd[buf][2][lane] + pd[buf][3][lane])) + bBd;
    float h2v = fast_tanh(sd);
    float sg = ((pg[buf][0][lane] + pg[buf][1][lane]) +
                (pg[buf][2][lane] + pg[buf][3][lane])) + bBg;
    float gc = fmaxf(sg, 0.f) + __logf(1.f + __expf(-fabsf(sg))) + mind;
    h2c[w][lane] = h2v;
    // intra-wave handoff: no barrier

    // ---- stage C (redundant per wave): 64 MACs, broadcast reads ----
    float d0 = 0.f, d1 = 0.f, d2 = 0.f, d3 = 0.f;
#pragma unroll
    for (int g = 0; g < 16; g++) {
      float4 hv = *(const float4*)&h2c[w][g * 4];
      d0 += hv.x * wC[g * 4 + 0];
      d1 += hv.y * wC[g * 4 + 1];
      d2 += hv.z * wC[g * 4 + 2];
      d3 += hv.w * wC[g * 4 + 3];
    }
    float dc = fminf(fmaxf((d0 + d1) + (d2 + d3) + bC, -maxd), maxd);

    // ---- y update (redundant per wave, own copy) ----
    float yo = ymine;
    float yn = yo + dc * yo * hh + gc * fminf(fmaxf(yo, -10.f), 10.f) * nz * sq;
    yn = fminf(fmaxf(yn, 0.01f), 10.f);
    y_s[w][lane] = yn;
    ymine = yn;
    if (w == 0) out[(long)b * 32768 + (i + 1) * 64 + lane] = yn;
    if (w == 1) outB[((long)b * 512 + i + 1) * 64 + lane] = f2b(yn);
  }
}

// ---------------------------------------------------------------------------
__global__ __launch_bounds__(256) void prep_weights(
    const float* __restrict__ in_W, const float* __restrict__ Wq,
    const float* __restrict__ Wk, const float* __restrict__ Wv,
    const float* __restrict__ Wo, const float* __restrict__ fW1,
    const float* __restrict__ fW2,
    u16* __restrict__ inWt, u16* __restrict__ qkvWt, u16* __restrict__ Wot,
    u16* __restrict__ fW1t, u16* __restrict__ fW2t) {
  const int z = blockIdx.z, layer = blockIdx.y, tile = blockIdx.x;
  const float* src; u16* dst; int R, C, nl;
  switch (z) {
    case 0: src = in_W; dst = inWt; R = 64; C = 128; nl = 1; break;
    case 1: src = Wq + layer * 16384; dst = qkvWt + layer * 49152; R = 128; C = 128; nl = 4; break;
    case 2: src = Wk + layer * 16384; dst = qkvWt + layer * 49152 + 16384; R = 128; C = 128; nl = 4; break;
    case 3: src = Wv + layer * 16384; dst = qkvWt + layer * 49152 + 32768; R = 128; C = 128; nl = 4; break;
    case 4: src = Wo + layer * 16384; dst = Wot + layer * 16384; R = 128; C = 128; nl = 4; break;
    case 5: src = fW1 + layer * 65536; dst = fW1t + layer * 65536; R = 128; C = 512; nl = 4; break;
    default: src = fW2 + layer * 65536; dst = fW2t + layer * 65536; R = 512; C = 128; nl = 4; break;
  }
  const int nt = (R / 32) * (C / 32);
  if (layer >= nl || tile >= nt) return;
  const int tpr = C / 32;
  const int r0 = (tile / tpr) * 32, c0 = (tile % tpr) * 32;
  __shared__ float tl[32][33];
  const int tx = threadIdx.x & 31, ty = threadIdx.x >> 5;
#pragma unroll
  for (int p = 0; p < 4; p++)
    tl[ty + 8 * p][tx] = src[(long)(r0 + ty + 8 * p) * C + c0 + tx];
  __syncthreads();
#pragma unroll
  for (int p = 0; p < 4; p++)
    dst[(long)(c0 + ty + 8 * p) * R + r0 + tx] = f2b(tl[tx][ty + 8 * p]);
}

// ---------------------------------------------------------------------------
// bf16 MFMA GEMM. MODE 1: bf16+relu. MODE 3: bf16.
// ---------------------------------------------------------------------------
template <int MODE>
__global__ __launch_bounds__(256) void mfma_gemm(
    const u16* __restrict__ A, const u16* __restrict__ Bt,
    const float* __restrict__ bias, u16* __restrict__ outB, int K, int N) {
  __shared__ u16 As[128 * 40];
  __shared__ u16 Bs[64 * 40];
  const int t = threadIdx.x;
  const int nb = blockIdx.x * 64;
  const long mb = (long)blockIdx.y * 128;
  const int lane = t & 63, wave = t >> 6;
  const int wm = (wave >> 1) * 64, wn = (wave & 1) * 32;
  const int fr = lane & 15, quad = lane >> 4;

  f32x4 zero = {0.f, 0.f, 0.f, 0.f};
  f32x4 acc[4][2];
#pragma unroll
  for (int mi = 0; mi < 4; mi++)
#pragma unroll
    for (int ni = 0; ni < 2; ni++) acc[mi][ni] = zero;

  for (int k0 = 0; k0 < K; k0 += 32) {
#pragma unroll
    for (int p = 0; p < 2; p++) {
      int idx = t + p * 256, row = idx >> 2, seg = idx & 3;
      int4 v = *(const int4*)&A[(mb + row) * K + k0 + seg * 8];
      *(int4*)&As[row * 40 + seg * 8] = v;
    }
    {
      int row = t >> 2, seg = t & 3;
      int4 v = *(const int4*)&Bt[(long)(nb + row) * K + k0 + seg * 8];
      *(int4*)&Bs[row * 40 + seg * 8] = v;
    }
    __syncthreads();
    bf16x8 af[4], bfr[2];
#pragma unroll
    for (int mi = 0; mi < 4; mi++)
      af[mi] = *(const bf16x8*)&As[(wm + mi * 16 + fr) * 40 + quad * 8];
#pragma unroll
    for (int ni = 0; ni < 2; ni++)
      bfr[ni] = *(const bf16x8*)&Bs[(wn + ni * 16 + fr) * 40 + quad * 8];
#pragma unroll
    for (int mi = 0; mi < 4; mi++)
#pragma unroll
      for (int ni = 0; ni < 2; ni++)
        acc[mi][ni] = __builtin_amdgcn_mfma_f32_16x16x32_bf16(
            af[mi], bfr[ni], acc[mi][ni], 0, 0, 0);
    __syncthreads();
  }

#pragma unroll
  for (int mi = 0; mi < 4; mi++)
#pragma unroll
    for (int ni = 0; ni < 2; ni++) {
      int col = nb + wn + ni * 16 + fr;
      float bv = bias[col];
#pragma unroll
      for (int r = 0; r < 4; r++) {
        long row = mb + wm + mi * 16 + quad * 4 + r;
        float v = acc[mi][ni][r] + bv;
        if (MODE == 1) {
          outB[row * N + col] = f2b(fmaxf(v, 0.f));
        } else {
          outB[row * N + col] = f2b(v);
        }
      }
    }
}

// ---------------------------------------------------------------------------
// Fused GEMM + residual(bf16) + LayerNorm -> bf16. Tile 64x128, 512 blocks.
// ---------------------------------------------------------------------------
__global__ __launch_bounds__(256) void gemm_ln(
    const u16* __restrict__ A, const u16* __restrict__ Bt,
    const float* __restrict__ bias, const u16* __restrict__ resid,
    const float* __restrict__ gamma, const float* __restrict__ beta,
    u16* __restrict__ outB, int K) {
  __shared__ u16 As[64 * 40];
  __shared__ u16 Bs[128 * 40];
  __shared__ float s1[2][64], s2[2][64];
  const int t = threadIdx.x;
  const long mb = (long)blockIdx.x * 64;
  const int lane = t & 63, wave = t >> 6;
  const int wm = (wave >> 1) * 32, wn = (wave & 1) * 64;
  const int fr = lane & 15, quad = lane >> 4;

  f32x4 zero = {0.f, 0.f, 0.f, 0.f};
  f32x4 acc[2][4];
#pragma unroll
  for (int mi = 0; mi < 2; mi++)
#pragma unroll
    for (int ni = 0; ni < 4; ni++) acc[mi][ni] = zero;

  for (int k0 = 0; k0 < K; k0 += 32) {
    {
      int row = t >> 2, seg = t & 3;
      *(int4*)&As[row * 40 + seg * 8] =
          *(const int4*)&A[(mb + row) * K + k0 + seg * 8];
    }
#pragma unroll
    for (int p = 0; p < 2; p++) {
      int idx = t + p * 256, row = idx >> 2, seg = idx & 3;
      *(int4*)&Bs[row * 40 + seg * 8] =
          *(const int4*)&Bt[(long)row * K + k0 + seg * 8];
    }
    __syncthreads();
    bf16x8 af[2], bfr[4];
#pragma unroll
    for (int mi = 0; mi < 2; mi++)
      af[mi] = *(const bf16x8*)&As[(wm + mi * 16 + fr) * 40 + quad * 8];
#pragma unroll
    for (int ni = 0; ni < 4; ni++)
      bfr[ni] = *(const bf16x8*)&Bs[(wn + ni * 16 + fr) * 40 + quad * 8];
#pragma unroll
    for (int mi = 0; mi < 2; mi++)
#pragma unroll
      for (int ni = 0; ni < 4; ni++)
        acc[mi][ni] = __builtin_amdgcn_mfma_f32_16x16x32_bf16(
            af[mi], bfr[ni], acc[mi][ni], 0, 0, 0);
    __syncthreads();
  }

  float bv[4], gv[4], be[4];
#pragma unroll
  for (int ni = 0; ni < 4; ni++) {
    int col = wn + ni * 16 + fr;
    bv[ni] = bias[col];
    gv[ni] = gamma[col];
    be[ni] = beta[col];
  }

#pragma unroll
  for (int mi = 0; mi < 2; mi++) {
#pragma unroll
    for (int r = 0; r < 4; r++) {
      int rloc = wm + mi * 16 + quad * 4 + r;
      long row = mb + rloc;
      float s = 0.f, ss = 0.f;
#pragma unroll
      for (int ni = 0; ni < 4; ni++) {
        int col = wn + ni * 16 + fr;
        float v = acc[mi][ni][r] + bv[ni] + b2f(resid[row * DD + col]);
        acc[mi][ni][r] = v;
        s += v;
        ss += v * v;
      }
      s += __shfl_xor(s, 1); ss += __shfl_xor(ss, 1);
      s += __shfl_xor(s, 2); ss += __shfl_xor(ss, 2);
      s += __shfl_xor(s, 4); ss += __shfl_xor(ss, 4);
      s += __shfl_xor(s, 8); ss += __shfl_xor(ss, 8);
      if (fr == 0) {
        s1[wn >> 6][rloc] = s;
        s2[wn >> 6][rloc] = ss;
      }
    }
  }
  __syncthreads();

#pragma unroll
  for (int mi = 0; mi < 2; mi++) {
#pragma unroll
    for (int r = 0; r < 4; r++) {
      int rloc = wm + mi * 16 + quad * 4 + r;
      long row = mb + rloc;
      float sum = s1[0][rloc] + s1[1][rloc];
      float sumsq = s2[0][rloc] + s2[1][rloc];
      float mean = sum * (1.f / 128.f);
      float var = sumsq * (1.f / 128.f) - mean * mean;
      float rstd = rsqrtf(var + 1e-5f);
#pragma unroll
      for (int ni = 0; ni < 4; ni++) {
        int col = wn + ni * 16 + fr;
        float o = (acc[mi][ni][r] - mean) * rstd * gv[ni] + be[ni];
        outB[row * DD + col] = f2b(o);
      }
    }
  }
}

// ---------------------------------------------------------------------------
// Fused QKV-projection + flash attention. One block per (b,h), 512 blocks,
// 2 blocks/CU (64.3 KB LDS). Block computes its head's Q/K/V (512x16 each,
// K=128 — head slices exactly partition the QKV GEMM) into LDS, then runs
// the S^T-orientation online-softmax loop (verified round 8).
// ---------------------------------------------------------------------------
__global__ __launch_bounds__(256, 2) void qkv_attn(
    const u16* __restrict__ xb, const u16* __restrict__ qkvW,
    const float* __restrict__ bq, const float* __restrict__ bk,
    const float* __restrict__ bv, u16* __restrict__ Og) {
  const int bh = blockIdx.x;
  const int b = bh >> 3, h = bh & 7;
  __shared__ u16 Ks[512 * 24];     // [key][d]  (24 KB)
  __shared__ u16 Vt[16 * 520];     // [d][key]  (16.3 KB)
  __shared__ u16 Qs[512 * 24];     // [q][d]    (24 KB)
  const int t = threadIdx.x;
  const int w = t >> 6, lane = t & 63;
  const int fr = lane & 15, quad = lane >> 4;
  const long obase = ((long)b * SS) * DD + h * 16;
  const u16* xrow = xb + (long)b * SS * DD;

  // ---- head weight B-frags (register-resident) ----
  const u16* Wq_h = qkvW + (h * 16) * 128;
  const u16* Wk_h = qkvW + 16384 + (h * 16) * 128;
  const u16* Wv_h = qkvW + 32768 + (h * 16) * 128;
  bf16x8 wqf[4], wkf[4], wvf[4];
#pragma unroll
  for (int c = 0; c < 4; c++) {
    wqf[c] = *(const bf16x8*)&Wq_h[fr * 128 + c * 32 + quad * 8];
    wkf[c] = *(const bf16x8*)&Wk_h[fr * 128 + c * 32 + quad * 8];
    wvf[c] = *(const bf16x8*)&Wv_h[fr * 128 + c * 32 + quad * 8];
  }
  const float bqv = bq[h * 16 + fr];
  const float bkv = bk[h * 16 + fr];
  const float bvv = bv[h * 16 + fr];
  const f32x4 z4 = {0.f, 0.f, 0.f, 0.f};

  // ---- project Q/K/V for this head into LDS ----
  for (int tile = w; tile < 32; tile += 4) {
    const int t0 = tile * 16;
    bf16x8 af[4];
#pragma unroll
    for (int c = 0; c < 4; c++)
      af[c] = *(const bf16x8*)&xrow[(t0 + fr) * 128 + c * 32 + quad * 8];
    f32x4 qa = z4, ka = z4, va = z4;
#pragma unroll
    for (int c = 0; c < 4; c++) {
      qa = __builtin_amdgcn_mfma_f32_16x16x32_bf16(af[c], wqf[c], qa, 0, 0, 0);
      ka = __builtin_amdgcn_mfma_f32_16x16x32_bf16(af[c], wkf[c], ka, 0, 0, 0);
      va = __builtin_amdgcn_mfma_f32_16x16x32_bf16(af[c], wvf[c], va, 0, 0, 0);
    }
    // C-layout: lane holds (d = fr, row = t0 + quad*4 + r)
#pragma unroll
    for (int r = 0; r < 4; r++) {
      int row = t0 + quad * 4 + r;
      Qs[row * 24 + fr] = f2b(qa[r] + bqv);
      Ks[row * 24 + fr] = f2b(ka[r] + bkv);
      Vt[fr * 520 + row] = f2b(va[r] + bvv);
    }
  }
  __syncthreads();

  // ---- flash attention (S^T orientation) ----
  const float scale = 0.25f;                 // 1/sqrt(16)
  const int addrA = (((quad & 1) * 32) + fr) * 4;
  const int addrB = addrA + 64;
  const bool loTile = (quad < 2);

  for (int qt = w; qt < 32; qt += 4) {
    const int q0 = qt * 16;
    bf16x8 qf = {0, 0, 0, 0, 0, 0, 0, 0};
    if (quad < 2)
      qf = *(const bf16x8*)&Qs[(q0 + fr) * 24 + quad * 8];
    f32x4 oacc = {0.f, 0.f, 0.f, 0.f};
    float mrun = -1e30f, lrun = 0.f;

    for (int kt = 0; kt < 16; kt++) {
      const int k0 = kt * 32;
      bf16x8 kf0 = {0, 0, 0, 0, 0, 0, 0, 0};
      bf16x8 kf1 = {0, 0, 0, 0, 0, 0, 0, 0};
      if (quad < 2) {
        kf0 = *(const bf16x8*)&Ks[(k0 + fr) * 24 + quad * 8];
        kf1 = *(const bf16x8*)&Ks[(k0 + 16 + fr) * 24 + quad * 8];
      }
      f32x4 slo = __builtin_amdgcn_mfma_f32_16x16x32_bf16(kf0, qf, z4, 0, 0, 0);
      f32x4 shi = __builtin_amdgcn_mfma_f32_16x16x32_bf16(kf1, qf, z4, 0, 0, 0);
      float s[8];
#pragma unroll
      for (int r = 0; r < 4; r++) {
        s[r] = slo[r] * scale;
        s[4 + r] = shi[r] * scale;
      }
      float mx = s[0];
#pragma unroll
      for (int r = 1; r < 8; r++) mx = fmaxf(mx, s[r]);
      mx = fmaxf(mx, __shfl_xor(mx, 16));
      mx = fmaxf(mx, __shfl_xor(mx, 32));
      float nm = fmaxf(mrun, mx);
      float alpha = __expf(mrun - nm);
      mrun = nm;
      float p[8], rs = 0.f;
#pragma unroll
      for (int r = 0; r < 8; r++) {
        p[r] = __expf(s[r] - nm);
        rs += p[r];
      }
      rs += __shfl_xor(rs, 16);
      rs += __shfl_xor(rs, 32);
      lrun = lrun * alpha + rs;
#pragma unroll
      for (int r = 0; r < 4; r++) oacc[r] *= alpha;

      int pk0 = ((int)f2b(p[1]) << 16) | f2b(p[0]);
      int pk1 = ((int)f2b(p[3]) << 16) | f2b(p[2]);
      int pk2 = ((int)f2b(p[5]) << 16) | f2b(p[4]);
      int pk3 = ((int)f2b(p[7]) << 16) | f2b(p[6]);
      int B0a = __builtin_amdgcn_ds_bpermute(addrA, pk0);
      int B0b = __builtin_amdgcn_ds_bpermute(addrA, pk2);
      int B1a = __builtin_amdgcn_ds_bpermute(addrA, pk1);
      int B1b = __builtin_amdgcn_ds_bpermute(addrA, pk3);
      int B2a = __builtin_amdgcn_ds_bpermute(addrB, pk0);
      int B2b = __builtin_amdgcn_ds_bpermute(addrB, pk2);
      int B3a = __builtin_amdgcn_ds_bpermute(addrB, pk1);
      int B3b = __builtin_amdgcn_ds_bpermute(addrB, pk3);
      union { int i[4]; bf16x8 v; } pu;
      pu.i[0] = loTile ? B0a : B0b;
      pu.i[1] = loTile ? B1a : B1b;
      pu.i[2] = loTile ? B2a : B2b;
      pu.i[3] = loTile ? B3a : B3b;
      bf16x8 vf = *(const bf16x8*)&Vt[fr * 520 + k0 + quad * 8];
      oacc = __builtin_amdgcn_mfma_f32_16x16x32_bf16(vf, pu.v, oacc, 0, 0, 0);
    }

    float inv = __fdividef(1.f, lrun);
    ushort4 o;
    o.x = f2b(oacc[0] * inv);
    o.y = f2b(oacc[1] * inv);
    o.z = f2b(oacc[2] * inv);
    o.w = f2b(oacc[3] * inv);
    *(ushort4*)&Og[obase + (long)(q0 + fr) * DD + quad * 4] = o;
  }
}

// ---------------------------------------------------------------------------
__global__ __launch_bounds__(128) void pool_kernel(const u16* __restrict__ X,
                                                   float* __restrict__ P) {
  const int b = blockIdx.x, c = threadIdx.x;
  float acc = 0.f;
  for (int s = 0; s < SS; s++) acc += b2f(X[((long)b * SS + s) * DD + c]);
  P[b * DD + c] = acc * (1.f / 512.f);
}

__global__ __launch_bounds__(64) void cls_kernel(
    const float* __restrict__ P, const float* __restrict__ W1,
    const float* __restrict__ b1, const float* __restrict__ W2,
    const float* __restrict__ b2, float* __restrict__ L) {
  const int b = blockIdx.x, t = threadIdx.x;
  __shared__ float sp[128];
  __shared__ float sh[64];
  sp[t] = P[b * DD + t];
  sp[t + 64] = P[b * DD + 64 + t];
  __syncthreads();
  float acc = b1[t];
  for (int k = 0; k < 128; k++) acc += sp[k] * W1[k * 64 + t];
  sh[t] = fmaxf(acc, 0.f);
  __syncthreads();
  if (t < 5) {
    float acc2 = b2[t];
    for (int k = 0; k < 64; k++) acc2 += sh[k] * W2[k * 5 + t];
    L[b * 5 + t] = acc2;
  }
}

// ---------------------------------------------------------------------------
extern "C" void kernel_launch(void* const* d_in, const int* in_sizes, int n_in,
                              void* d_out, int out_size, void* d_ws, size_t ws_size,
                              hipStream_t stream) {
  const float* ts    = (const float*)d_in[0];
  const float* noise = (const float*)d_in[2];
  const float* dW1   = (const float*)d_in[3];
  const float* db1   = (const float*)d_in[4];
  const float* dW2   = (const float*)d_in[5];
  const float* db2   = (const float*)d_in[6];
  const float* dW3   = (const float*)d_in[7];
  const float* db3   = (const float*)d_in[8];
  const float* gW1   = (const float*)d_in[9];
  const float* gb1   = (const float*)d_in[10];
  const float* gW2   = (const float*)d_in[11];
  const float* gb2   = (const float*)d_in[12];
  const float* mind  = (const float*)d_in[13];
  const float* maxd  = (const float*)d_in[14];
  const float* in_W  = (const float*)d_in[15];
  const float* in_b  = (const float*)d_in[16];
  const float* Wq    = (const float*)d_in[17];
  const float* bq    = (const float*)d_in[18];
  const float* Wk    = (const float*)d_in[19];
  const float* bk    = (const float*)d_in[20];
  const float* Wv    = (const float*)d_in[21];
  const float* bv    = (const float*)d_in[22];
  const float* Wo    = (const float*)d_in[23];
  const float* bo    = (const float*)d_in[24];
  const float* ln1s  = (const float*)d_in[25];
  const float* ln1b  = (const float*)d_in[26];
  const float* fW1   = (const float*)d_in[27];
  const float* fb1   = (const float*)d_in[28];
  const float* fW2   = (const float*)d_in[29];
  const float* fb2   = (const float*)d_in[30];
  const float* ln2s  = (const float*)d_in[31];
  const float* ln2b  = (const float*)d_in[32];
  const float* cW1   = (const float*)d_in[33];
  const float* cb1   = (const float*)d_in[34];
  const float* cW2   = (const float*)d_in[35];
  const float* cb2   = (const float*)d_in[36];

  float* logits = (float*)d_out;
  float* sde    = logits + BB * 5;

  // Workspace (all-bf16 residual stream):
  char* W = (char*)d_ws;
  u16*  bxb    = (u16*)(W);                   //  8 MB bf16 x
  u16*  bh     = (u16*)(W + (8u << 20));      // 32 MB FFN hidden
  u16*  bob    = (u16*)(W + (40u << 20));     //  8 MB bf16 attn out
  u16*  bsb    = (u16*)(W + (48u << 20));     //  4 MB bf16 sde feats
  u16*  wts    = (u16*)(W + (52u << 20));     // ~1.5 MB bf16 weights
  float* bp    = (float*)(W + (54u << 20));   // pooled 64x128

  u16* inWt  = wts;                 // [128][64]
  u16* qkvWt = inWt + 8192;         // [4][3][128][128]
  u16* Wot   = qkvWt + 196608;      // [4][128][128]
  u16* fW1t  = Wot + 65536;         // [4][512][128]
  u16* fW2t  = fW1t + 262144;       // [4][128][512]

  prep_weights<<<dim3(64, 4, 7), 256, 0, stream>>>(in_W, Wq, Wk, Wv, Wo, fW1, fW2,
                                                   inWt, qkvWt, Wot, fW1t, fW2t);

  sde_kernel<<<64, 512, 0, stream>>>(ts, noise, dW1, db1, dW2, db2, dW3, db3,
                                     gW1, gb1, gW2, gb2, mind, maxd, sde, bsb);

  // x = sde @ in_W + in_b  (bf16)
  mfma_gemm<3><<<dim3(2, 256), 256, 0, stream>>>(bsb, inWt, in_b, bxb, 64, 128);

  for (int l = 0; l < 4; l++) {
    qkv_attn<<<BB * NHD, 256, 0, stream>>>(bxb, qkvWt + l * 49152,
                                           bq + l * DD, bk + l * DD, bv + l * DD,
                                           bob);
    gemm_ln<<<512, 256, 0, stream>>>(bob, Wot + l * 16384, bo + l * DD, bxb,
                                     ln1s + l * DD, ln1b + l * DD, bxb, 128);
    mfma_gemm<1><<<dim3(8, 256), 256, 0, stream>>>(bxb, fW1t + l * 65536,
                                                   fb1 + l * 512, bh, 128, 512);
    gemm_ln<<<512, 256, 0, stream>>>(bh, fW2t + l * 65536, fb2 + l * DD, bxb,
                                     ln2s + l * DD, ln2b + l * DD, bxb, 512);
  }

  pool_kernel<<<BB, 128, 0, stream>>>(bxb, bp);
  cls_kernel<<<BB, 64, 0, stream>>>(bp, cW1, cb1, cW2, cb2, logits);
}